// Round 8
// baseline (423.929 us; speedup 1.0000x reference)
//
#include <hip/hip_runtime.h>
#include <cstddef>

// Problem constants
#define D_MODEL 768
#define NHEAD   12
#define DHEAD   64
#define RANK    32
#define SEQ     1024
#define BATCH   8
#define BM      8192      // BATCH*SEQ

typedef __attribute__((ext_vector_type(8))) short short8;
typedef __attribute__((ext_vector_type(4))) float floatx4;

__device__ inline ushort f2b(float f) {           // fp32 -> bf16 RNE
  union { float f; unsigned u; } v; v.f = f;
  unsigned r = v.u + 0x7fffu + ((v.u >> 16) & 1u);
  return (ushort)(r >> 16);
}
__device__ inline float b2f(ushort h) {
  union { unsigned u; float f; } v; v.u = ((unsigned)h) << 16;
  return v.f;
}
// pack two fp32 -> bf16x2 dword
__device__ inline unsigned pk2(float a, float b) {
  return ((__float_as_uint(b) + 0x8000u) & 0xffff0000u) |
         ((__float_as_uint(a) + 0x8000u) >> 16);
}
// tanh-form GELU with fast exp (max |err vs erf-GELU| ~1e-3)
__device__ inline float fast_gelu(float x) {
  float z = 0.79788456080286536f * (x + 0.044715f * x * x * x);
  float e = __expf(2.f * z);
  float t = 1.f - 2.f / (e + 1.f);
  return 0.5f * x * (1.f + t);
}

// ---------------------------------------------------------------------------
__global__ __launch_bounds__(256) void f2b_kernel(
    const float* __restrict__ in, ushort* __restrict__ out, int n) {
  int i = (blockIdx.x * 256 + threadIdx.x) * 4;
  if (i >= n) return;
  float4 v = *(const float4*)(in + i);
  ushort4 o;
  o.x = f2b(v.x); o.y = f2b(v.y); o.z = f2b(v.z); o.w = f2b(v.w);
  *(ushort4*)(out + i) = o;
}

// ---------------------------------------------------------------------------
// All three QKV low-rank combines in one launch (grid.y selects q/k/v):
// Wt[y][c=h*64+k][d] = sum_r P[h,d,r] * Vw[h,r,k]
// ---------------------------------------------------------------------------
__global__ __launch_bounds__(256) void combine_qkv_kernel(
    const float* __restrict__ Pq, const float* __restrict__ Vq,
    const float* __restrict__ Pk, const float* __restrict__ Vk,
    const float* __restrict__ Pv, const float* __restrict__ Vv,
    ushort* __restrict__ Wt) {
  int which = blockIdx.y;
  const float* P  = which == 0 ? Pq : (which == 1 ? Pk : Pv);
  const float* Vw = which == 0 ? Vq : (which == 1 ? Vk : Vv);
  ushort* W = Wt + (size_t)which * D_MODEL * D_MODEL;
  int idx = blockIdx.x * 256 + threadIdx.x;
  if (idx >= D_MODEL * NHEAD * DHEAD) return;
  int c = idx / D_MODEL;
  int d = idx - c * D_MODEL;
  int h = c >> 6, k = c & 63;
  const float* p = P + ((size_t)h * D_MODEL + d) * RANK;
  const float* v = Vw + (size_t)h * RANK * DHEAD + k;
  float s = 0.f;
#pragma unroll
  for (int r = 0; r < RANK; r++) s += p[r] * v[(size_t)r * DHEAD];
  W[(size_t)c * D_MODEL + d] = f2b(s);
}

__global__ __launch_bounds__(256) void concat_bias_kernel(
    const float* __restrict__ bq, const float* __restrict__ bk,
    const float* __restrict__ bv, float* __restrict__ out) {
  int i = blockIdx.x * 256 + threadIdx.x;
  if (i >= 2304) return;
  out[i] = (i < 768) ? bq[i] : (i < 1536 ? bk[i - 768] : bv[i - 1536]);
}

// ---------------------------------------------------------------------------
// Six weight preps in one launch (block-range decode):
// transposes (fp32 (R,C) -> bf16 (C,R)): U1(768,384) V1(384,3072)
//   U2(3072,384) V2(384,768) Vo(384,768)
// plus straight f2b copy of Uo (768x384) for the Wot GEMM's Bt operand.
// ---------------------------------------------------------------------------
__global__ __launch_bounds__(256) void prep_weights_kernel(
    const float* __restrict__ U1, const float* __restrict__ V1,
    const float* __restrict__ U2, const float* __restrict__ V2,
    const float* __restrict__ Vo, const float* __restrict__ Uo,
    ushort* __restrict__ U1t, ushort* __restrict__ V1t,
    ushort* __restrict__ U2t, ushort* __restrict__ V2t,
    ushort* __restrict__ VoT, ushort* __restrict__ Uob) {
  __shared__ float t[32][33];
  int blk = blockIdx.x;
  if (blk >= 3168) {                 // Uo f2b copy: 288 blocks x 1024 elems
    int i = (blk - 3168) * 1024 + threadIdx.x * 4;
    float4 v = *(const float4*)(Uo + i);
    ushort4 o;
    o.x = f2b(v.x); o.y = f2b(v.y); o.z = f2b(v.z); o.w = f2b(v.w);
    *(ushort4*)(Uob + i) = o;
    return;
  }
  const float* in; ushort* out; int R, C, bx, by;
  if (blk < 288)       { in = U1; out = U1t; R = 768;  C = 384;  int i = blk;        bx = i % 12; by = i / 12; }
  else if (blk < 1440) { in = V1; out = V1t; R = 384;  C = 3072; int i = blk - 288;  bx = i % 96; by = i / 96; }
  else if (blk < 2592) { in = U2; out = U2t; R = 3072; C = 384;  int i = blk - 1440; bx = i % 12; by = i / 12; }
  else if (blk < 2880) { in = V2; out = V2t; R = 384;  C = 768;  int i = blk - 2592; bx = i % 24; by = i / 24; }
  else                 { in = Vo; out = VoT; R = 384;  C = 768;  int i = blk - 2880; bx = i % 24; by = i / 24; }
  int c0 = bx * 32, r0 = by * 32;
  int lx = threadIdx.x & 31, ly = threadIdx.x >> 5;
#pragma unroll
  for (int i = 0; i < 32; i += 8)
    t[ly + i][lx] = in[(size_t)(r0 + ly + i) * C + c0 + lx];
  __syncthreads();
#pragma unroll
  for (int i = 0; i < 32; i += 8)
    out[(size_t)(c0 + ly + i) * R + r0 + lx] = f2b(t[lx][ly + i]);
}

// ---------------------------------------------------------------------------
// 256x256-tile bf16 MFMA GEMM (R8): 512 threads, 8 waves (2M x 4N), BK=32.
// R7 diagnosis: 128^2 piped kernel at 22% MfmaUtil, DS 0.75 ops/MFMA.
// 256^2 per-wave 128x64 output (acc[8][4]) -> A-frag reuse 4x, B-frag 8x:
// DS drops to 0.5 ops/MFMA (12 reads + 4 writes per 32 MFMAs) and each
// barrier covers 2x the MFMA work. Same R5/R7-proven pipeline skeleton:
// reg-staged dbuf, ONE raw barrier/step, lgkmcnt-only drain (VMEM for step
// s+2 stays in flight), setprio around MFMA cluster.
// Bank swizzle slot ^= (row>>1)&3: all 8 bank-group bases hit exactly 2x
// (the free 2-way floor, m136). LDS = 64 KB (same as R7, compiles/runs).
// Used ONLY for grids >= ~280 blocks (QKV, V1); small-N GEMMs keep the
// 128^2 kernel (1 block/CU here would starve CUs).
// ---------------------------------------------------------------------------
template <int OUTMODE, int BIAS, int GELU>
__global__ __launch_bounds__(512, 2) void gemm_mfma256_kernel(
    const ushort* __restrict__ A, const ushort* __restrict__ Bt,
    const float* __restrict__ bias, void* __restrict__ C,
    void* __restrict__ C2, void* __restrict__ C3,
    int M, int N, int K) {
  __shared__ __align__(16) ushort Als[2][256 * 32];
  __shared__ __align__(16) ushort Bls[2][256 * 32];
  const int tid  = threadIdx.x;
  const int lane = tid & 63;
  const int quad = lane >> 4, l16 = lane & 15;
  const int wu   = __builtin_amdgcn_readfirstlane(tid >> 6);   // 0..7
  const int wrow = (wu >> 2) * 128, wcol = (wu & 3) * 64;
  const int row0 = blockIdx.x * 256, col0 = blockIdx.y * 256;

  // staging: thread covers rows r = (t>>2) + 128p (p=0,1), 16B slot = t&3
  const int r_ = tid >> 2, sl_ = tid & 3;
  const ushort* Ag = A + (size_t)(row0 + r_) * K + sl_ * 8;
  const ushort* Bg = Bt + (size_t)(col0 + r_) * K + sl_ * 8;
  // swizzled write offset; ((r+128)>>1)&3 == (r>>1)&3 so one constant works
  const int loff = r_ * 32 + ((sl_ ^ ((r_ >> 1) & 3)) << 3);
  // swizzled read slot (row&~15 doesn't affect (row>>1)&3 -> l16-only)
  const int srd = (quad ^ ((l16 >> 1) & 3)) << 3;

  const int nsteps = K >> 5;
  short8 ast[2], bst[2];

  // prologue: step-0 tile -> regs -> buf0; then issue step-1 loads
#pragma unroll
  for (int p = 0; p < 2; p++) {
    ast[p] = *(const short8*)(Ag + (size_t)(128 * p) * K);
    bst[p] = *(const short8*)(Bg + (size_t)(128 * p) * K);
  }
#pragma unroll
  for (int p = 0; p < 2; p++) {
    *(short8*)(&Als[0][0] + loff + p * (128 * 32)) = ast[p];
    *(short8*)(&Bls[0][0] + loff + p * (128 * 32)) = bst[p];
  }
#pragma unroll
  for (int p = 0; p < 2; p++) {
    ast[p] = *(const short8*)(Ag + (size_t)(128 * p) * K + 32);
    bst[p] = *(const short8*)(Bg + (size_t)(128 * p) * K + 32);
  }
  asm volatile("s_waitcnt lgkmcnt(0)" ::: "memory");
  __builtin_amdgcn_s_barrier();
  asm volatile("" ::: "memory");

  floatx4 acc[8][4] = {};

  for (int s = 0; s < nsteps; s++) {
    const int cur = s & 1;

    // (1) write staged regs (step s+1) -> buf[cur^1]
    if (s + 1 < nsteps) {
#pragma unroll
      for (int p = 0; p < 2; p++) {
        *(short8*)(&Als[cur ^ 1][0] + loff + p * (128 * 32)) = ast[p];
        *(short8*)(&Bls[cur ^ 1][0] + loff + p * (128 * 32)) = bst[p];
      }
      // (2) issue step s+2 global loads (land under compute)
      if (s + 2 < nsteps) {
        const int ko = (s + 2) * 32;
#pragma unroll
        for (int p = 0; p < 2; p++) {
          ast[p] = *(const short8*)(Ag + (size_t)(128 * p) * K + ko);
          bst[p] = *(const short8*)(Bg + (size_t)(128 * p) * K + ko);
        }
      }
    }

    // (3) compute step s from buf[cur]
    __builtin_amdgcn_s_setprio(1);
    short8 af[8], bf[4];
#pragma unroll
    for (int mt = 0; mt < 8; mt++)
      af[mt] = *(const short8*)(&Als[cur][0] + (wrow + mt * 16 + l16) * 32 + srd);
#pragma unroll
    for (int nt = 0; nt < 4; nt++)
      bf[nt] = *(const short8*)(&Bls[cur][0] + (wcol + nt * 16 + l16) * 32 + srd);
#pragma unroll
    for (int mt = 0; mt < 8; mt++)
#pragma unroll
      for (int nt = 0; nt < 4; nt++)
        acc[mt][nt] = __builtin_amdgcn_mfma_f32_16x16x32_bf16(
            af[mt], bf[nt], acc[mt][nt], 0, 0, 0);
    __builtin_amdgcn_s_setprio(0);

    // (4) one barrier per step (drain own ds_writes only; VMEM in flight)
    if (s + 1 < nsteps) {
      asm volatile("s_waitcnt lgkmcnt(0)" ::: "memory");
      __builtin_amdgcn_s_barrier();
      asm volatile("" ::: "memory");
    }
  }

#pragma unroll
  for (int mt = 0; mt < 8; mt++) {
#pragma unroll
    for (int nt = 0; nt < 4; nt++) {
      int colg = col0 + wcol + nt * 16 + l16;
      float bv_ = BIAS ? bias[colg] : 0.f;
      float v4[4];
#pragma unroll
      for (int r = 0; r < 4; r++) {
        float v = acc[mt][nt][r] + bv_;
        if (GELU) v = fast_gelu(v);
        v4[r] = v;
      }
      int rowg0 = row0 + wrow + mt * 16 + quad * 4;
      if (OUTMODE == 3) {
        int seg = col0 / 768;       // 768 = 3*256: tiles never straddle segs
        int cl = colg - seg * 768;
        if (seg == 2) {
          ushort4 o;
          o.x = f2b(v4[0]); o.y = f2b(v4[1]); o.z = f2b(v4[2]); o.w = f2b(v4[3]);
          *(ushort4*)((ushort*)C3 + (size_t)cl * BM + rowg0) = o;
        } else {
          ushort* dst = (seg == 0) ? (ushort*)C : (ushort*)C2;
          float sc = (seg == 0) ? 0.125f : 1.f;   // fold 1/sqrt(64) into Q
#pragma unroll
          for (int r = 0; r < 4; r++)
            dst[(size_t)(rowg0 + r) * D_MODEL + cl] = f2b(v4[r] * sc);
        }
      } else {
#pragma unroll
        for (int r = 0; r < 4; r++)
          ((ushort*)C)[(size_t)(rowg0 + r) * N + colg] = f2b(v4[r]);
      }
    }
  }
}

// ---------------------------------------------------------------------------
// bf16 MFMA GEMM v2 (R7, verified): 128^2, BK=64, reg-staged dbuf pipeline.
// Kept for small-N GEMMs (y1, FFN1, V2) where 256-tiles would starve CUs.
// ---------------------------------------------------------------------------
template <int OUTMODE, int BIAS, int GELU>
__global__ __launch_bounds__(256, 2) void gemm_mfma_kernel(
    const ushort* __restrict__ A, const ushort* __restrict__ Bt,
    const float* __restrict__ bias, void* __restrict__ C,
    void* __restrict__ C2, void* __restrict__ C3,
    int M, int N, int K) {
  __shared__ __align__(16) ushort Als[2][128 * 64];
  __shared__ __align__(16) ushort Bls[2][128 * 64];
  const int tid  = threadIdx.x;
  const int lane = tid & 63;
  const int quad = lane >> 4, l16 = lane & 15;
  const int wu   = __builtin_amdgcn_readfirstlane(tid >> 6);
  const int wrow = (wu >> 1) * 64, wcol = (wu & 1) * 64;
  const int row0 = blockIdx.x * 128, col0 = blockIdx.y * 128;

  const int r_ = tid >> 3, sl_ = tid & 7;
  const ushort* Ag = A + (size_t)(row0 + r_) * K + sl_ * 8;
  const ushort* Bg = Bt + (size_t)(col0 + r_) * K + sl_ * 8;
  const int loff = r_ * 64 + ((sl_ ^ (r_ & 7)) << 3);

  const int nsteps = K >> 6;
  short8 ast[4], bst[4];

#pragma unroll
  for (int p = 0; p < 4; p++) {
    ast[p] = *(const short8*)(Ag + (size_t)(32 * p) * K);
    bst[p] = *(const short8*)(Bg + (size_t)(32 * p) * K);
  }
#pragma unroll
  for (int p = 0; p < 4; p++) {
    *(short8*)(&Als[0][0] + loff + p * (32 * 64)) = ast[p];
    *(short8*)(&Bls[0][0] + loff + p * (32 * 64)) = bst[p];
  }
#pragma unroll
  for (int p = 0; p < 4; p++) {
    ast[p] = *(const short8*)(Ag + (size_t)(32 * p) * K + 64);
    bst[p] = *(const short8*)(Bg + (size_t)(32 * p) * K + 64);
  }
  asm volatile("s_waitcnt lgkmcnt(0)" ::: "memory");
  __builtin_amdgcn_s_barrier();
  asm volatile("" ::: "memory");

  floatx4 acc[4][4] = {};

  for (int s = 0; s < nsteps; s++) {
    const int cur = s & 1;

    if (s + 1 < nsteps) {
#pragma unroll
      for (int p = 0; p < 4; p++) {
        *(short8*)(&Als[cur ^ 1][0] + loff + p * (32 * 64)) = ast[p];
        *(short8*)(&Bls[cur ^ 1][0] + loff + p * (32 * 64)) = bst[p];
      }
      if (s + 2 < nsteps) {
        const int ko = (s + 2) * 64;
#pragma unroll
        for (int p = 0; p < 4; p++) {
          ast[p] = *(const short8*)(Ag + (size_t)(32 * p) * K + ko);
          bst[p] = *(const short8*)(Bg + (size_t)(32 * p) * K + ko);
        }
      }
    }

    __builtin_amdgcn_s_setprio(1);
#pragma unroll
    for (int kk = 0; kk < 2; kk++) {
      short8 af[4], bf[4];
#pragma unroll
      for (int mt = 0; mt < 4; mt++) {
        int row = wrow + mt * 16 + l16;
        af[mt] = *(const short8*)(&Als[cur][0] + row * 64
                                  + (((kk * 4 + quad) ^ (l16 & 7)) << 3));
      }
#pragma unroll
      for (int nt = 0; nt < 4; nt++) {
        int row = wcol + nt * 16 + l16;
        bf[nt] = *(const short8*)(&Bls[cur][0] + row * 64
                                  + (((kk * 4 + quad) ^ (l16 & 7)) << 3));
      }
#pragma unroll
      for (int mt = 0; mt < 4; mt++)
#pragma unroll
        for (int nt = 0; nt < 4; nt++)
          acc[mt][nt] = __builtin_amdgcn_mfma_f32_16x16x32_bf16(
              af[mt], bf[nt], acc[mt][nt], 0, 0, 0);
    }
    __builtin_amdgcn_s_setprio(0);

    if (s + 1 < nsteps) {
      asm volatile("s_waitcnt lgkmcnt(0)" ::: "memory");
      __builtin_amdgcn_s_barrier();
      asm volatile("" ::: "memory");
    }
  }

#pragma unroll
  for (int mt = 0; mt < 4; mt++) {
#pragma unroll
    for (int nt = 0; nt < 4; nt++) {
      int colg = col0 + wcol + nt * 16 + l16;
      float bv_ = BIAS ? bias[colg] : 0.f;
      float v4[4];
#pragma unroll
      for (int r = 0; r < 4; r++) {
        float v = acc[mt][nt][r] + bv_;
        if (GELU) v = fast_gelu(v);
        v4[r] = v;
      }
      int rowg0 = row0 + wrow + mt * 16 + quad * 4;
      if (OUTMODE == 3) {
        int seg = col0 / 768;
        int cl = colg - seg * 768;
        if (seg == 2) {
          ushort4 o;
          o.x = f2b(v4[0]); o.y = f2b(v4[1]); o.z = f2b(v4[2]); o.w = f2b(v4[3]);
          *(ushort4*)((ushort*)C3 + (size_t)cl * BM + rowg0) = o;
        } else {
          ushort* dst = (seg == 0) ? (ushort*)C : (ushort*)C2;
          float sc = (seg == 0) ? 0.125f : 1.f;
#pragma unroll
          for (int r = 0; r < 4; r++)
            dst[(size_t)(rowg0 + r) * D_MODEL + cl] = f2b(v4[r] * sc);
        }
      } else {
#pragma unroll
        for (int r = 0; r < 4; r++)
          ((ushort*)C)[(size_t)(rowg0 + r) * N + colg] = f2b(v4[r]);
      }
    }
  }
}

// ---------------------------------------------------------------------------
// 128x64-tile bf16 MFMA GEMM (+bias), bf16 out. grid (M/128, N/64).
// Kept only for the tiny Wot GEMM (768x768, K=384).
// ---------------------------------------------------------------------------
template <int BIAS>
__global__ __launch_bounds__(256) void gemm_n64_kernel(
    const ushort* __restrict__ A, const ushort* __restrict__ Bt,
    const float* __restrict__ bias, ushort* __restrict__ C,
    int M, int N, int K) {
  __shared__ __align__(16) ushort Als[128 * 32];
  __shared__ __align__(16) ushort Bls[64 * 32];
  const int tid  = threadIdx.x;
  const int lane = tid & 63;
  const int quad = lane >> 4, l16 = lane & 15;
  const int wu   = __builtin_amdgcn_readfirstlane(tid >> 6);
  const int row0 = blockIdx.x * 128, col0 = blockIdx.y * 64;

  floatx4 acc[2][4] = {};

  for (int k0 = 0; k0 < K; k0 += 32) {
    __syncthreads();
#pragma unroll
    for (int is = 0; is < 2; is++) {
      int c = is * 256 + wu * 64 + lane;
      int m = c >> 2, kk = (c & 3) << 3;
      const ushort* ga = A + (size_t)(row0 + m) * K + (k0 + kk);
      ushort* la = Als + (size_t)(is * 256 + wu * 64) * 8;
      __builtin_amdgcn_global_load_lds(
          (const __attribute__((address_space(1))) void*)ga,
          (__attribute__((address_space(3))) void*)la, 16, 0, 0);
    }
    {
      int c = wu * 64 + lane;
      int m = c >> 2, kk = (c & 3) << 3;
      const ushort* gb = Bt + (size_t)(col0 + m) * K + (k0 + kk);
      ushort* lb = Bls + (size_t)(wu * 64) * 8;
      __builtin_amdgcn_global_load_lds(
          (const __attribute__((address_space(1))) void*)gb,
          (__attribute__((address_space(3))) void*)lb, 16, 0, 0);
    }
    __syncthreads();

    short8 af[2], bf[4];
#pragma unroll
    for (int mt = 0; mt < 2; mt++)
      af[mt] = *(const short8*)(Als + ((wu * 32 + mt * 16 + l16) * 32 + quad * 8));
#pragma unroll
    for (int nt = 0; nt < 4; nt++)
      bf[nt] = *(const short8*)(Bls + ((nt * 16 + l16) * 32 + quad * 8));
#pragma unroll
    for (int mt = 0; mt < 2; mt++)
#pragma unroll
      for (int nt = 0; nt < 4; nt++)
        acc[mt][nt] = __builtin_amdgcn_mfma_f32_16x16x32_bf16(
            af[mt], bf[nt], acc[mt][nt], 0, 0, 0);
  }

#pragma unroll
  for (int mt = 0; mt < 2; mt++) {
#pragma unroll
    for (int nt = 0; nt < 4; nt++) {
      int colg = col0 + nt * 16 + l16;
      float bv_ = BIAS ? bias[colg] : 0.f;
      int rowg0 = row0 + wu * 32 + mt * 16 + quad * 4;
#pragma unroll
      for (int r = 0; r < 4; r++)
        C[(size_t)(rowg0 + r) * N + colg] = f2b(acc[mt][nt][r] + bv_);
    }
  }
}

// ---------------------------------------------------------------------------
// Split-K bf16 MFMA GEMM (fp32 partials) + reduce.
// grid (M/128, N/128, S) -- x = M-block (same-XCD A reuse).
// ---------------------------------------------------------------------------
__global__ __launch_bounds__(256) void gemm_mfma_splitk_kernel(
    const ushort* __restrict__ A, const ushort* __restrict__ Bt,
    float* __restrict__ Cpart, int M, int N, int Ktot, int Kper) {
  __shared__ __align__(16) ushort Als[128 * 32];
  __shared__ __align__(16) ushort Bls[128 * 32];
  const int tid  = threadIdx.x;
  const int lane = tid & 63;
  const int quad = lane >> 4, l16 = lane & 15;
  const int wu   = __builtin_amdgcn_readfirstlane(tid >> 6);
  const int wrow = (wu >> 1) * 64, wcol = (wu & 1) * 64;
  const int row0 = blockIdx.x * 128, col0 = blockIdx.y * 128;
  const int kbase = blockIdx.z * Kper;
  float* Cz = Cpart + (size_t)blockIdx.z * M * N;

  floatx4 acc[4][4] = {};

  for (int k0 = kbase; k0 < kbase + Kper; k0 += 32) {
    __syncthreads();
#pragma unroll
    for (int is = 0; is < 2; is++) {
      int c = is * 256 + wu * 64 + lane;
      int m = c >> 2, kk = (c & 3) << 3;
      const ushort* ga = A + (size_t)(row0 + m) * Ktot + (k0 + kk);
      ushort* la = Als + (size_t)(is * 256 + wu * 64) * 8;
      __builtin_amdgcn_global_load_lds(
          (const __attribute__((address_space(1))) void*)ga,
          (__attribute__((address_space(3))) void*)la, 16, 0, 0);
      const ushort* gb = Bt + (size_t)(col0 + m) * Ktot + (k0 + kk);
      ushort* lb = Bls + (size_t)(is * 256 + wu * 64) * 8;
      __builtin_amdgcn_global_load_lds(
          (const __attribute__((address_space(1))) void*)gb,
          (__attribute__((address_space(3))) void*)lb, 16, 0, 0);
    }
    __syncthreads();

    short8 af[4], bf[4];
#pragma unroll
    for (int mt = 0; mt < 4; mt++)
      af[mt] = *(const short8*)(Als + ((wrow + mt * 16 + l16) * 32 + quad * 8));
#pragma unroll
    for (int nt = 0; nt < 4; nt++)
      bf[nt] = *(const short8*)(Bls + ((wcol + nt * 16 + l16) * 32 + quad * 8));
#pragma unroll
    for (int mt = 0; mt < 4; mt++)
#pragma unroll
      for (int nt = 0; nt < 4; nt++)
        acc[mt][nt] = __builtin_amdgcn_mfma_f32_16x16x32_bf16(
            af[mt], bf[nt], acc[mt][nt], 0, 0, 0);
  }

#pragma unroll
  for (int mt = 0; mt < 4; mt++)
#pragma unroll
    for (int nt = 0; nt < 4; nt++) {
      int colg = col0 + wcol + nt * 16 + l16;
      int rowg0 = row0 + wrow + mt * 16 + quad * 4;
#pragma unroll
      for (int r = 0; r < 4; r++)
        Cz[(size_t)(rowg0 + r) * N + colg] = acc[mt][nt][r];
    }
}

__global__ __launch_bounds__(256) void reduce_splitk_kernel(
    const float* __restrict__ part, ushort* __restrict__ out, int n, int S) {
  int i = (blockIdx.x * 256 + threadIdx.x) * 4;
  if (i >= n) return;
  float4 a = *(const float4*)(part + i);
  for (int s = 1; s < S; s++) {
    float4 b = *(const float4*)(part + (size_t)s * n + i);
    a.x += b.x; a.y += b.y; a.z += b.z; a.w += b.w;
  }
  ushort4 o;
  o.x = f2b(a.x); o.y = f2b(a.y); o.z = f2b(a.z); o.w = f2b(a.w);
  *(ushort4*)(out + i) = o;
}

// ---------------------------------------------------------------------------
// MFMA flash attention v11 (R5-verified). UNCHANGED.
// ---------------------------------------------------------------------------
__global__ __launch_bounds__(256, 3) void attn_mfma_kernel(
    const ushort* __restrict__ Q, const ushort* __restrict__ K,
    const ushort* __restrict__ Vt, const float* __restrict__ mask,
    ushort* __restrict__ O) {
  // bijective decode: bid = (slot*8 + qt)*8 + xcd ; grp = slot*8 + xcd
  const int bid  = blockIdx.x;          // 768 blocks
  const int xcd  = bid & 7;
  const int rest = bid >> 3;            // 0..95
  const int qt   = rest & 7;
  const int grp  = (rest >> 3) * 8 + xcd;   // 0..95, grp%8 == xcd
  const int h = grp % 12, b = grp / 12;

  const int tid = threadIdx.x;
  const int lane = tid & 63;
  const int quad = lane >> 4, l16 = lane & 15;
  const int wu = __builtin_amdgcn_readfirstlane(tid >> 6);
  const int qrow0 = qt * 128 + wu * 32;

  __shared__ __align__(16) ushort Ks[2][64 * 64];   // [buf][key][dh], swz slots
  __shared__ __align__(16) ushort Vts[2][64 * 64];  // [buf][dh][key], swz slots
  __shared__ __align__(16) float Msk[SEQ];          // whole mask row

  // one-time mask row preload (1024 floats, one float4/thread)
  *(float4*)(Msk + tid * 4) = *(const float4*)(mask + (size_t)b * SEQ + tid * 4);

  short8 qf[2][2];
#pragma unroll
  for (int rt = 0; rt < 2; rt++) {
    const ushort* qp = Q + ((size_t)(b * SEQ + qrow0 + rt * 16 + l16)) * D_MODEL
                     + h * DHEAD + quad * 8;
    qf[rt][0] = *(const short8*)qp;
    qf[rt][1] = *(const short8*)(qp + 32);
  }

  // staging decomposition: 64 rows x 8 slots, 2 rounds of 32 rows
  const int j0 = tid >> 3, ck = tid & 7;
  const ushort* Kg = K + ((size_t)(b * SEQ + j0)) * D_MODEL + h * DHEAD + ck * 8;
  const ushort* Vg = Vt + ((size_t)(h * DHEAD + j0)) * BM + b * SEQ + ck * 8;
  const int kloff = j0 * 64 + ((ck ^ (j0 & 7)) << 3);   // (row&7) const over p

  // prologue: chunk 0 -> regs -> buf0; then issue chunk-1 loads
  short8 kst[2], vst[2];
#pragma unroll
  for (int p = 0; p < 2; p++) {
    kst[p] = *(const short8*)(Kg + (size_t)(p * 32) * D_MODEL);
    vst[p] = *(const short8*)(Vg + (size_t)p * (32 * BM));
  }
#pragma unroll
  for (int p = 0; p < 2; p++) {
    *(short8*)(&Ks[0][0] + kloff + p * (32 * 64)) = kst[p];
    *(short8*)(&Vts[0][0] + kloff + p * (32 * 64)) = vst[p];
  }
#pragma unroll
  for (int p = 0; p < 2; p++) {
    kst[p] = *(const short8*)(Kg + (size_t)(64 + p * 32) * D_MODEL);
    vst[p] = *(const short8*)(Vg + 64 + (size_t)p * (32 * BM));
  }
  asm volatile("s_waitcnt lgkmcnt(0)" ::: "memory");
  __builtin_amdgcn_s_barrier();
  asm volatile("" ::: "memory");

  float lsum[2] = {0.f, 0.f};
  floatx4 o_acc[2][4] = {};

  for (int n0 = 0; n0 < SEQ; n0 += 64) {
    const int cur = (n0 >> 6) & 1;

    // (1) write staged regs (chunk i+1) -> buf[cur^1]
    if (n0 + 64 < SEQ) {
#pragma unroll
      for (int p = 0; p < 2; p++) {
        *(short8*)(&Ks[cur ^ 1][0] + kloff + p * (32 * 64)) = kst[p];
        *(short8*)(&Vts[cur ^ 1][0] + kloff + p * (32 * 64)) = vst[p];
      }
      // (2) issue chunk i+2 global loads (land during compute below)
      if (n0 + 128 < SEQ) {
#pragma unroll
        for (int p = 0; p < 2; p++) {
          kst[p] = *(const short8*)(Kg + (size_t)(n0 + 128 + p * 32) * D_MODEL);
          vst[p] = *(const short8*)(Vg + (n0 + 128) + (size_t)p * (32 * BM));
        }
      }
    }

    // (3) compute chunk i from buf[cur]
    __builtin_amdgcn_s_setprio(1);
    unsigned UA[2][4], UB[2][4];
#pragma unroll
    for (int ct = 0; ct < 4; ct++) {
      int krow = ct * 16 + l16;
      int sa = (quad ^ (l16 & 7)) << 3;                 // swizzled 16B slot
      const ushort* kbp = &Ks[cur][0] + krow * 64;
      short8 ka = *(const short8*)(kbp + sa);           // K[krow][quad*8..]
      short8 kb = *(const short8*)(kbp + (sa ^ 32));    // K[krow][32+quad*8..]
      float4 mk = *(const float4*)(Msk + n0 + ct * 16 + quad * 4);
#pragma unroll
      for (int rt = 0; rt < 2; rt++) {
        floatx4 st = {};
        st = __builtin_amdgcn_mfma_f32_16x16x32_bf16(ka, qf[rt][0], st, 0, 0, 0);
        st = __builtin_amdgcn_mfma_f32_16x16x32_bf16(kb, qf[rt][1], st, 0, 0, 0);
        float e0 = __expf(st[0] + mk.x);     // Q pre-scaled by 1/sqrt(dh)
        float e1 = __expf(st[1] + mk.y);
        float e2 = __expf(st[2] + mk.z);
        float e3 = __expf(st[3] + mk.w);
        lsum[rt] += (e0 + e1) + (e2 + e3);
        UA[rt][ct] = pk2(e0, e1);            // keys quad*4+0,1 (query l16)
        UB[rt][ct] = pk2(e2, e3);            // keys quad*4+2,3
      }
    }

#pragma unroll
    for (int kk = 0; kk < 2; kk++) {
      short8 pa[2];
#pragma unroll
      for (int rt = 0; rt < 2; rt++) {
        // in-register P transpose: dest quad q, dword w <- keys q*8+2w,+2w+1
        unsigned a0 = UA[rt][2 * kk], a2 = UA[rt][2 * kk + 1];
        unsigned b1 = UB[rt][2 * kk], b3 = UB[rt][2 * kk + 1];
        asm("v_permlane32_swap_b32 %0, %1" : "+v"(a0), "+v"(a2));
        asm("v_permlane16_swap_b32 %0, %1" : "+v"(a0), "+v"(a2));
        asm("v_permlane32_swap_b32 %0, %1" : "+v"(b1), "+v"(b3));
        asm("v_permlane16_swap_b32 %0, %1" : "+v"(b1), "+v"(b3));
        int4 t;
        t.x = (int)a0;   // keys q*8+0,1
        t.y = (int)b1;   // keys q*8+2,3
        t.z = (int)a2;   // keys q*8+4,5
        t.w = (int)b3;   // keys q*8+6,7
        pa[rt] = *(short8*)&t;
      }
#pragma unroll
      for (int dt = 0; dt < 4; dt++) {
        int vr = dt * 16 + l16;
        short8 vb = *(const short8*)(&Vts[cur][0] + vr * 64
                                     + (((kk * 4 + quad) ^ (l16 & 7)) << 3));
#pragma unroll
        for (int rt = 0; rt < 2; rt++)
          o_acc[rt][dt] = __builtin_amdgcn_mfma_f32_16x16x32_bf16(
              pa[rt], vb, o_acc[rt][dt], 0, 0, 0);
      }
    }
    __builtin_amdgcn_s_setprio(0);

    // (4) one barrier per chunk (drain own ds_writes first)
    if (n0 + 64 < SEQ) {
      asm volatile("s_waitcnt lgkmcnt(0)" ::: "memory");
      __builtin_amdgcn_s_barrier();
      asm volatile("" ::: "memory");
    }
  }

#pragma unroll
  for (int rt = 0; rt < 2; rt++) {
    float l = lsum[rt];
    l += __shfl_xor(l, 16);
    l += __shfl_xor(l, 32);
    float inv = 1.f / l;
    int lanebase = lane & 48;
#pragma unroll
    for (int rr = 0; rr < 4; rr++) {
      int iv = __builtin_amdgcn_ds_bpermute((lanebase | (quad * 4 + rr)) << 2,
                                            __float_as_int(inv));
      float invr = __int_as_float(iv);
      size_t rowg = (size_t)(b * SEQ + qrow0 + rt * 16 + quad * 4 + rr);
#pragma unroll
      for (int dt = 0; dt < 4; dt++)
        O[rowg * D_MODEL + h * DHEAD + dt * 16 + l16] = f2b(o_acc[rt][dt][rr] * invr);
    }
  }
}

// ---------------------------------------------------------------------------
// out = LayerNorm(Ain + Bin)*g + bt. Bin bf16. Ain fp32 or bf16.
// ---------------------------------------------------------------------------
template <int AIN_BF16, int OUT_FP32, int OUT_BF16>
__global__ __launch_bounds__(256) void add_ln_kernel(
    const float* __restrict__ Ainf, const ushort* __restrict__ Ainb,
    const ushort* __restrict__ Binb,
    const float* __restrict__ g, const float* __restrict__ bt,
    float* __restrict__ outf, ushort* __restrict__ outb) {
  const int row = blockIdx.x, tid = threadIdx.x;
  __shared__ float red[4];
  float v[3];
  float s = 0.f;
#pragma unroll
  for (int u = 0; u < 3; u++) {
    int c = tid + u * 256;
    float a = AIN_BF16 ? b2f(Ainb[(size_t)row * 768 + c]) : Ainf[(size_t)row * 768 + c];
    v[u] = a + b2f(Binb[(size_t)row * 768 + c]);
    s += v[u];
  }
#pragma unroll
  for (int off = 32; off > 0; off >>= 1) s += __shfl_down(s, off);
  if ((tid & 63) == 0) red[tid >> 6] = s;
  __syncthreads();
  float mu = (red[0] + red[1] + red[2] + red[3]) * (1.f / 768.f);
  float s2 = 0.f;
#pragma unroll
  for (int u = 0; u < 3; u++) { float d = v[u] - mu; s2 += d * d; }
#pragma unroll
  for (int off = 32; off > 0; off >>= 1) s2 += __shfl_down(s2, off);
  __syncthreads();
  if ((tid & 63) == 0) red[tid >> 6] = s2;
  __syncthreads();
  float var = (red[0] + red[1] + red[2] + red[3]) * (1.f / 768.f);
  float inv = rsqrtf(var + 1e-12f);
#pragma unroll
  for (int u = 0; u < 3; u++) {
    int c = tid + u * 256;
    float r = g[c] * (v[u] - mu) * inv + bt[c];
    if (OUT_FP32) outf[(size_t)row * 768 + c] = r;
    if (OUT_BF16) outb[(size_t)row * 768 + c] = f2b(r);
  }
}

// ---------------------------------------------------------------------------
extern "C" void kernel_launch(void* const* d_in, const int* in_sizes, int n_in,
                              void* d_out, int out_size, void* d_ws, size_t ws_size,
                              hipStream_t stream) {
  const float* x    = (const float*)d_in[0];
  const float* mask = (const float*)d_in[1];
  const float* Pq   = (const float*)d_in[2];
  const float* Vq   = (const float*)d_in[3];
  const float* bq   = (const float*)d_in[4];
  const float* Pk   = (const float*)d_in[5];
  const float* Vk   = (const float*)d_in[6];
  const float* bk   = (const float*)d_in[7];
  const float* Pv   = (const float*)d_in[8];
  const float* Vv   = (const float*)d_in[9];
  const float* bv   = (const float*)d_in[10];
  const float* Uo   = (const float*)d_in[11];
  const float* Vo   = (const float*)d_in[12];
  const float* bo   = (const float*)d_in[13];
  const float* U1   = (const float*)d_in[14];
  const float* V1   = (const float*)d_in[15];
  const float* b1   = (const float*)d_in[16];
  const float* U2   = (const float*)d_in[17];
  const float* V2   = (const float*)d_in[18];
  const float* b2   = (const float*)d_in[19];
  const float* g1   = (const float*)d_in[20];
  const float* be1  = (const float*)d_in[21];
  const float* g2   = (const float*)d_in[22];
  const float* be2  = (const float*)d_in[23];

  // --- workspace carve (bytes, 256-aligned) ---
  char* w = (char*)d_ws;
  auto alloc = [&](size_t bytes) -> char* {
    char* p = w; w += (bytes + 255) & ~(size_t)255; return p;
  };
  ushort* xb     = (ushort*)alloc((size_t)BM * 768 * 2);
  ushort* Wqkvt  = (ushort*)alloc((size_t)2304 * 768 * 2);
  float*  ball   = (float*)alloc(2304 * 4);
  ushort* VoT    = (ushort*)alloc(768 * 384 * 2);   // Vo^T bf16 (A operand)
  ushort* Uob    = (ushort*)alloc(768 * 384 * 2);   // Uo bf16 (Bt operand)
  ushort* Wot    = (ushort*)alloc(768 * 768 * 2);   // Vo^T @ Uo^T = Wo^T
  ushort* U1t    = (ushort*)alloc(384 * 768 * 2);
  ushort* V1t    = (ushort*)alloc((size_t)3072 * 384 * 2);
  ushort* U2t    = (ushort*)alloc((size_t)384 * 3072 * 2);
  ushort* V2t    = (ushort*)alloc(768 * 384 * 2);
  ushort* Qb     = (ushort*)alloc((size_t)BM * 768 * 2);
  ushort* Kb     = (ushort*)alloc((size_t)BM * 768 * 2);
  ushort* Vtb    = (ushort*)alloc((size_t)768 * BM * 2);
  ushort* attnb  = (ushort*)alloc((size_t)BM * 768 * 2);
  ushort* mtb    = (ushort*)alloc((size_t)BM * 384 * 2);   // mid / t2
  ushort* y1b    = (ushort*)alloc((size_t)BM * 768 * 2);
  ushort* x1b    = (ushort*)alloc((size_t)BM * 768 * 2);
  float*  part   = (float*)alloc((size_t)4 * BM * 384 * 4);
  // aliases (dead-buffer reuse)
  ushort* hiddenb = Qb;             // Qb..attnb (50.3 MB) dead after y1 GEMM
  ushort* y2b     = y1b;            // y1b dead after LN1
  float*  outp    = (float*)d_out;

  // 1) conversions / weight prep
  f2b_kernel<<<(BM * 768) / 1024, 256, 0, stream>>>(x, xb, BM * 768);
  combine_qkv_kernel<<<dim3(2304, 3), 256, 0, stream>>>(Pq, Vq, Pk, Vk, Pv, Vv, Wqkvt);
  concat_bias_kernel<<<9, 256, 0, stream>>>(bq, bk, bv, ball);
  prep_weights_kernel<<<3456, 256, 0, stream>>>(U1, V1, U2, V2, Vo, Uo,
                                                U1t, V1t, U2t, V2t, VoT, Uob);
  // Wot[n][d] = sum_r Vo^T[n][r] * Uo[d][r]  (= Wo[d][n], the Bt operand for y1)
  gemm_n64_kernel<0><<<dim3(6, 12), 256, 0, stream>>>(VoT, Uob, nullptr, Wot, 768, 768, 384);

  // 2) fused QKV = x @ [Wq|Wk|Wv] + bias  (256^2 piped GEMM, grid 32x9)
  gemm_mfma256_kernel<3, 1, 0><<<dim3(32, 9), 512, 0, stream>>>(
      xb, Wqkvt, ball, Qb, Kb, Vtb, BM, 2304, 768);

  // 3) MFMA flash attention (dbuf 1-barrier pipeline) -> bf16 (B*M, 768)
  attn_mfma_kernel<<<dim3(768), 256, 0, stream>>>(Qb, Kb, Vtb, mask, attnb);

  // 4) attn out-projection: y1 = attn @ Wo + bo  (128^2 piped GEMM)
  gemm_mfma_kernel<1, 1, 0><<<dim3(64, 6), 256, 0, stream>>>(
      attnb, Wot, bo, y1b, nullptr, nullptr, BM, 768, 768);
  add_ln_kernel<0, 0, 1><<<BM, 256, 0, stream>>>(x, nullptr, y1b, g1, be1, nullptr, x1b);

  // 5) FFN (low rank) with fast GELU
  gemm_mfma_kernel<1, 0, 0><<<dim3(64, 3), 256, 0, stream>>>(
      x1b, U1t, nullptr, mtb, nullptr, nullptr, BM, 384, 768);
  gemm_mfma256_kernel<1, 1, 1><<<dim3(32, 12), 512, 0, stream>>>(
      mtb, V1t, b1, hiddenb, nullptr, nullptr, BM, 3072, 384);
  //    t2 = hidden @ U2 (K=3072): splitk S=2
  gemm_mfma_splitk_kernel<<<dim3(64, 3, 2), 256, 0, stream>>>(
      hiddenb, U2t, part, BM, 384, 3072, 1536);
  reduce_splitk_kernel<<<(BM * 384) / 1024, 256, 0, stream>>>(part, mtb, BM * 384, 2);
  gemm_mfma_kernel<1, 1, 0><<<dim3(64, 6), 256, 0, stream>>>(
      mtb, V2t, b2, y2b, nullptr, nullptr, BM, 768, 384);

  // 6) residual + LN2 -> output (fp32)
  add_ln_kernel<1, 1, 0><<<BM, 256, 0, stream>>>(nullptr, x1b, y2b, g2, be2, outp, nullptr);
}

// Round 9
// 389.340 us; speedup vs baseline: 1.0888x; 1.0888x over previous
//
#include <hip/hip_runtime.h>
#include <cstddef>

// Problem constants
#define D_MODEL 768
#define NHEAD   12
#define DHEAD   64
#define RANK    32
#define SEQ     1024
#define BATCH   8
#define BM      8192      // BATCH*SEQ

typedef __attribute__((ext_vector_type(8))) short short8;
typedef __attribute__((ext_vector_type(4))) float floatx4;

__device__ inline ushort f2b(float f) {           // fp32 -> bf16 RNE
  union { float f; unsigned u; } v; v.f = f;
  unsigned r = v.u + 0x7fffu + ((v.u >> 16) & 1u);
  return (ushort)(r >> 16);
}
__device__ inline float b2f(ushort h) {
  union { unsigned u; float f; } v; v.u = ((unsigned)h) << 16;
  return v.f;
}
// pack two fp32 -> bf16x2 dword
__device__ inline unsigned pk2(float a, float b) {
  return ((__float_as_uint(b) + 0x8000u) & 0xffff0000u) |
         ((__float_as_uint(a) + 0x8000u) >> 16);
}
// tanh-form GELU with fast exp (max |err vs erf-GELU| ~1e-3)
__device__ inline float fast_gelu(float x) {
  float z = 0.79788456080286536f * (x + 0.044715f * x * x * x);
  float e = __expf(2.f * z);
  float t = 1.f - 2.f / (e + 1.f);
  return 0.5f * x * (1.f + t);
}

// ---------------------------------------------------------------------------
// All three QKV low-rank combines in one launch (grid.y selects q/k/v):
// Wt[y][c=h*64+k][d] = sum_r P[h,d,r] * Vw[h,r,k]
// ---------------------------------------------------------------------------
__global__ __launch_bounds__(256) void combine_qkv_kernel(
    const float* __restrict__ Pq, const float* __restrict__ Vq,
    const float* __restrict__ Pk, const float* __restrict__ Vk,
    const float* __restrict__ Pv, const float* __restrict__ Vv,
    ushort* __restrict__ Wt) {
  int which = blockIdx.y;
  const float* P  = which == 0 ? Pq : (which == 1 ? Pk : Pv);
  const float* Vw = which == 0 ? Vq : (which == 1 ? Vk : Vv);
  ushort* W = Wt + (size_t)which * D_MODEL * D_MODEL;
  int idx = blockIdx.x * 256 + threadIdx.x;
  if (idx >= D_MODEL * NHEAD * DHEAD) return;
  int c = idx / D_MODEL;
  int d = idx - c * D_MODEL;
  int h = c >> 6, k = c & 63;
  const float* p = P + ((size_t)h * D_MODEL + d) * RANK;
  const float* v = Vw + (size_t)h * RANK * DHEAD + k;
  float s = 0.f;
#pragma unroll
  for (int r = 0; r < RANK; r++) s += p[r] * v[(size_t)r * DHEAD];
  W[(size_t)c * D_MODEL + d] = f2b(s);
}

__global__ __launch_bounds__(256) void concat_bias_kernel(
    const float* __restrict__ bq, const float* __restrict__ bk,
    const float* __restrict__ bv, float* __restrict__ out) {
  int i = blockIdx.x * 256 + threadIdx.x;
  if (i >= 2304) return;
  out[i] = (i < 768) ? bq[i] : (i < 1536 ? bk[i - 768] : bv[i - 1536]);
}

// ---------------------------------------------------------------------------
// Six weight preps in one launch (block-range decode):
// transposes (fp32 (R,C) -> bf16 (C,R)): U1(768,384) V1(384,3072)
//   U2(3072,384) V2(384,768) Vo(384,768)
// plus straight f2b copy of Uo (768x384) for the Wot GEMM's Bt operand.
// ---------------------------------------------------------------------------
__global__ __launch_bounds__(256) void prep_weights_kernel(
    const float* __restrict__ U1, const float* __restrict__ V1,
    const float* __restrict__ U2, const float* __restrict__ V2,
    const float* __restrict__ Vo, const float* __restrict__ Uo,
    ushort* __restrict__ U1t, ushort* __restrict__ V1t,
    ushort* __restrict__ U2t, ushort* __restrict__ V2t,
    ushort* __restrict__ VoT, ushort* __restrict__ Uob) {
  __shared__ float t[32][33];
  int blk = blockIdx.x;
  if (blk >= 3168) {                 // Uo f2b copy: 288 blocks x 1024 elems
    int i = (blk - 3168) * 1024 + threadIdx.x * 4;
    float4 v = *(const float4*)(Uo + i);
    ushort4 o;
    o.x = f2b(v.x); o.y = f2b(v.y); o.z = f2b(v.z); o.w = f2b(v.w);
    *(ushort4*)(Uob + i) = o;
    return;
  }
  const float* in; ushort* out; int R, C, bx, by;
  if (blk < 288)       { in = U1; out = U1t; R = 768;  C = 384;  int i = blk;        bx = i % 12; by = i / 12; }
  else if (blk < 1440) { in = V1; out = V1t; R = 384;  C = 3072; int i = blk - 288;  bx = i % 96; by = i / 96; }
  else if (blk < 2592) { in = U2; out = U2t; R = 3072; C = 384;  int i = blk - 1440; bx = i % 12; by = i / 12; }
  else if (blk < 2880) { in = V2; out = V2t; R = 384;  C = 768;  int i = blk - 2592; bx = i % 24; by = i / 24; }
  else                 { in = Vo; out = VoT; R = 384;  C = 768;  int i = blk - 2880; bx = i % 24; by = i / 24; }
  int c0 = bx * 32, r0 = by * 32;
  int lx = threadIdx.x & 31, ly = threadIdx.x >> 5;
#pragma unroll
  for (int i = 0; i < 32; i += 8)
    t[ly + i][lx] = in[(size_t)(r0 + ly + i) * C + c0 + lx];
  __syncthreads();
#pragma unroll
  for (int i = 0; i < 32; i += 8)
    out[(size_t)(c0 + ly + i) * R + r0 + lx] = f2b(t[lx][ly + i]);
}

// ---------------------------------------------------------------------------
// bf16 MFMA GEMM v2 (R7-verified structure): 128^2, BK=64, reg-staged dbuf,
// ONE raw barrier per K-step, lgkmcnt-only drain (VMEM for step s+2 stays in
// flight across the barrier), XOR-swizzled 16B slots both sides, setprio
// around the MFMA cluster.
// R9: AFP32 template param -- A operand read as fp32 and packed to bf16 at
// ds_write time (fuses the old f2b_kernel into QKV staging; loads still ride
// the in-flight pipeline since conversion happens at write, not issue).
// OUTMODE: 1 bf16 (M,N); 3 fused QKV (Q pre-scaled 1/8; V transposed out).
// grid (M/128, N/128): x = M-block (R6 XCD A-reuse).
// ---------------------------------------------------------------------------
template <int OUTMODE, int BIAS, int GELU, int AFP32 = 0>
__global__ __launch_bounds__(256, 2) void gemm_mfma_kernel(
    const ushort* __restrict__ A, const ushort* __restrict__ Bt,
    const float* __restrict__ bias, void* __restrict__ C,
    void* __restrict__ C2, void* __restrict__ C3,
    int M, int N, int K) {
  __shared__ __align__(16) ushort Als[2][128 * 64];
  __shared__ __align__(16) ushort Bls[2][128 * 64];
  const int tid  = threadIdx.x;
  const int lane = tid & 63;
  const int quad = lane >> 4, l16 = lane & 15;
  const int wu   = __builtin_amdgcn_readfirstlane(tid >> 6);
  const int wrow = (wu >> 1) * 64, wcol = (wu & 1) * 64;
  const int row0 = blockIdx.x * 128, col0 = blockIdx.y * 128;

  const int r_ = tid >> 3, sl_ = tid & 7;
  const ushort* Ag = A + (size_t)(row0 + r_) * K + sl_ * 8;
  const float*  Agf = (const float*)A + (size_t)(row0 + r_) * K + sl_ * 8;
  const ushort* Bg = Bt + (size_t)(col0 + r_) * K + sl_ * 8;
  const int loff = r_ * 64 + ((sl_ ^ (r_ & 7)) << 3);

  const int nsteps = K >> 6;
  short8 ast[4], bst[4];
  float4 asf[4][2];

  // helpers ---------------------------------------------------------------
  auto loadA = [&](int p, int ko) {
    if (AFP32) {
      asf[p][0] = *(const float4*)(Agf + (size_t)(32 * p) * K + ko);
      asf[p][1] = *(const float4*)(Agf + (size_t)(32 * p) * K + ko + 4);
    } else {
      ast[p] = *(const short8*)(Ag + (size_t)(32 * p) * K + ko);
    }
  };
  auto writeA = [&](int buf, int p) {
    if (AFP32) {
      int4 t;
      t.x = (int)pk2(asf[p][0].x, asf[p][0].y);
      t.y = (int)pk2(asf[p][0].z, asf[p][0].w);
      t.z = (int)pk2(asf[p][1].x, asf[p][1].y);
      t.w = (int)pk2(asf[p][1].z, asf[p][1].w);
      *(short8*)(&Als[buf][0] + loff + p * (32 * 64)) = *(short8*)&t;
    } else {
      *(short8*)(&Als[buf][0] + loff + p * (32 * 64)) = ast[p];
    }
  };

  // prologue: step-0 tile -> regs -> buf0; then issue step-1 loads
#pragma unroll
  for (int p = 0; p < 4; p++) {
    loadA(p, 0);
    bst[p] = *(const short8*)(Bg + (size_t)(32 * p) * K);
  }
#pragma unroll
  for (int p = 0; p < 4; p++) {
    writeA(0, p);
    *(short8*)(&Bls[0][0] + loff + p * (32 * 64)) = bst[p];
  }
#pragma unroll
  for (int p = 0; p < 4; p++) {
    loadA(p, 64);
    bst[p] = *(const short8*)(Bg + (size_t)(32 * p) * K + 64);
  }
  asm volatile("s_waitcnt lgkmcnt(0)" ::: "memory");
  __builtin_amdgcn_s_barrier();
  asm volatile("" ::: "memory");

  floatx4 acc[4][4] = {};

  for (int s = 0; s < nsteps; s++) {
    const int cur = s & 1;

    if (s + 1 < nsteps) {
#pragma unroll
      for (int p = 0; p < 4; p++) {
        writeA(cur ^ 1, p);
        *(short8*)(&Bls[cur ^ 1][0] + loff + p * (32 * 64)) = bst[p];
      }
      if (s + 2 < nsteps) {
        const int ko = (s + 2) * 64;
#pragma unroll
        for (int p = 0; p < 4; p++) {
          loadA(p, ko);
          bst[p] = *(const short8*)(Bg + (size_t)(32 * p) * K + ko);
        }
      }
    }

    __builtin_amdgcn_s_setprio(1);
#pragma unroll
    for (int kk = 0; kk < 2; kk++) {
      short8 af[4], bf[4];
#pragma unroll
      for (int mt = 0; mt < 4; mt++) {
        int row = wrow + mt * 16 + l16;
        af[mt] = *(const short8*)(&Als[cur][0] + row * 64
                                  + (((kk * 4 + quad) ^ (l16 & 7)) << 3));
      }
#pragma unroll
      for (int nt = 0; nt < 4; nt++) {
        int row = wcol + nt * 16 + l16;
        bf[nt] = *(const short8*)(&Bls[cur][0] + row * 64
                                  + (((kk * 4 + quad) ^ (l16 & 7)) << 3));
      }
#pragma unroll
      for (int mt = 0; mt < 4; mt++)
#pragma unroll
        for (int nt = 0; nt < 4; nt++)
          acc[mt][nt] = __builtin_amdgcn_mfma_f32_16x16x32_bf16(
              af[mt], bf[nt], acc[mt][nt], 0, 0, 0);
    }
    __builtin_amdgcn_s_setprio(0);

    if (s + 1 < nsteps) {
      asm volatile("s_waitcnt lgkmcnt(0)" ::: "memory");
      __builtin_amdgcn_s_barrier();
      asm volatile("" ::: "memory");
    }
  }

#pragma unroll
  for (int mt = 0; mt < 4; mt++) {
#pragma unroll
    for (int nt = 0; nt < 4; nt++) {
      int colg = col0 + wcol + nt * 16 + l16;
      float bv_ = BIAS ? bias[colg] : 0.f;
      float v4[4];
#pragma unroll
      for (int r = 0; r < 4; r++) {
        float v = acc[mt][nt][r] + bv_;
        if (GELU) v = fast_gelu(v);
        v4[r] = v;
      }
      int rowg0 = row0 + wrow + mt * 16 + quad * 4;
      if (OUTMODE == 3) {
        int seg = col0 / 768;
        int cl = colg - seg * 768;
        if (seg == 2) {
          ushort4 o;
          o.x = f2b(v4[0]); o.y = f2b(v4[1]); o.z = f2b(v4[2]); o.w = f2b(v4[3]);
          *(ushort4*)((ushort*)C3 + (size_t)cl * BM + rowg0) = o;
        } else {
          ushort* dst = (seg == 0) ? (ushort*)C : (ushort*)C2;
          float sc = (seg == 0) ? 0.125f : 1.f;   // fold 1/sqrt(64) into Q
#pragma unroll
          for (int r = 0; r < 4; r++)
            dst[(size_t)(rowg0 + r) * D_MODEL + cl] = f2b(v4[r] * sc);
        }
      } else {
#pragma unroll
        for (int r = 0; r < 4; r++)
          ((ushort*)C)[(size_t)(rowg0 + r) * N + colg] = f2b(v4[r]);
      }
    }
  }
}

// ---------------------------------------------------------------------------
// Piped split-K bf16 MFMA GEMM (R9): same R7 pipeline (reg-staged dbuf, one
// raw barrier/step, swizzled slots, setprio), K-range [kbase, kbase+Kper),
// fp32 partial output. grid (M/128, N/128, S).
// ---------------------------------------------------------------------------
__global__ __launch_bounds__(256, 2) void gemm_piped_splitk_kernel(
    const ushort* __restrict__ A, const ushort* __restrict__ Bt,
    float* __restrict__ Cpart, int M, int N, int Ktot, int Kper) {
  __shared__ __align__(16) ushort Als[2][128 * 64];
  __shared__ __align__(16) ushort Bls[2][128 * 64];
  const int tid  = threadIdx.x;
  const int lane = tid & 63;
  const int quad = lane >> 4, l16 = lane & 15;
  const int wu   = __builtin_amdgcn_readfirstlane(tid >> 6);
  const int wrow = (wu >> 1) * 64, wcol = (wu & 1) * 64;
  const int row0 = blockIdx.x * 128, col0 = blockIdx.y * 128;
  const int kbase = blockIdx.z * Kper;
  float* Cz = Cpart + (size_t)blockIdx.z * M * N;

  const int r_ = tid >> 3, sl_ = tid & 7;
  const ushort* Ag = A + (size_t)(row0 + r_) * Ktot + kbase + sl_ * 8;
  const ushort* Bg = Bt + (size_t)(col0 + r_) * Ktot + kbase + sl_ * 8;
  const int loff = r_ * 64 + ((sl_ ^ (r_ & 7)) << 3);

  const int nsteps = Kper >> 6;
  short8 ast[4], bst[4];

#pragma unroll
  for (int p = 0; p < 4; p++) {
    ast[p] = *(const short8*)(Ag + (size_t)(32 * p) * Ktot);
    bst[p] = *(const short8*)(Bg + (size_t)(32 * p) * Ktot);
  }
#pragma unroll
  for (int p = 0; p < 4; p++) {
    *(short8*)(&Als[0][0] + loff + p * (32 * 64)) = ast[p];
    *(short8*)(&Bls[0][0] + loff + p * (32 * 64)) = bst[p];
  }
#pragma unroll
  for (int p = 0; p < 4; p++) {
    ast[p] = *(const short8*)(Ag + (size_t)(32 * p) * Ktot + 64);
    bst[p] = *(const short8*)(Bg + (size_t)(32 * p) * Ktot + 64);
  }
  asm volatile("s_waitcnt lgkmcnt(0)" ::: "memory");
  __builtin_amdgcn_s_barrier();
  asm volatile("" ::: "memory");

  floatx4 acc[4][4] = {};

  for (int s = 0; s < nsteps; s++) {
    const int cur = s & 1;

    if (s + 1 < nsteps) {
#pragma unroll
      for (int p = 0; p < 4; p++) {
        *(short8*)(&Als[cur ^ 1][0] + loff + p * (32 * 64)) = ast[p];
        *(short8*)(&Bls[cur ^ 1][0] + loff + p * (32 * 64)) = bst[p];
      }
      if (s + 2 < nsteps) {
        const int ko = (s + 2) * 64;
#pragma unroll
        for (int p = 0; p < 4; p++) {
          ast[p] = *(const short8*)(Ag + (size_t)(32 * p) * Ktot + ko);
          bst[p] = *(const short8*)(Bg + (size_t)(32 * p) * Ktot + ko);
        }
      }
    }

    __builtin_amdgcn_s_setprio(1);
#pragma unroll
    for (int kk = 0; kk < 2; kk++) {
      short8 af[4], bf[4];
#pragma unroll
      for (int mt = 0; mt < 4; mt++) {
        int row = wrow + mt * 16 + l16;
        af[mt] = *(const short8*)(&Als[cur][0] + row * 64
                                  + (((kk * 4 + quad) ^ (l16 & 7)) << 3));
      }
#pragma unroll
      for (int nt = 0; nt < 4; nt++) {
        int row = wcol + nt * 16 + l16;
        bf[nt] = *(const short8*)(&Bls[cur][0] + row * 64
                                  + (((kk * 4 + quad) ^ (l16 & 7)) << 3));
      }
#pragma unroll
      for (int mt = 0; mt < 4; mt++)
#pragma unroll
        for (int nt = 0; nt < 4; nt++)
          acc[mt][nt] = __builtin_amdgcn_mfma_f32_16x16x32_bf16(
              af[mt], bf[nt], acc[mt][nt], 0, 0, 0);
    }
    __builtin_amdgcn_s_setprio(0);

    if (s + 1 < nsteps) {
      asm volatile("s_waitcnt lgkmcnt(0)" ::: "memory");
      __builtin_amdgcn_s_barrier();
      asm volatile("" ::: "memory");
    }
  }

#pragma unroll
  for (int mt = 0; mt < 4; mt++)
#pragma unroll
    for (int nt = 0; nt < 4; nt++) {
      int colg = col0 + wcol + nt * 16 + l16;
      int rowg0 = row0 + wrow + mt * 16 + quad * 4;
#pragma unroll
      for (int r = 0; r < 4; r++)
        Cz[(size_t)(rowg0 + r) * N + colg] = acc[mt][nt][r];
    }
}

__global__ __launch_bounds__(256) void reduce_splitk_kernel(
    const float* __restrict__ part, ushort* __restrict__ out, int n, int S) {
  int i = (blockIdx.x * 256 + threadIdx.x) * 4;
  if (i >= n) return;
  float4 a = *(const float4*)(part + i);
  for (int s = 1; s < S; s++) {
    float4 b = *(const float4*)(part + (size_t)s * n + i);
    a.x += b.x; a.y += b.y; a.z += b.z; a.w += b.w;
  }
  ushort4 o;
  o.x = f2b(a.x); o.y = f2b(a.y); o.z = f2b(a.z); o.w = f2b(a.w);
  *(ushort4*)(out + i) = o;
}

// ---------------------------------------------------------------------------
// 128x64-tile bf16 MFMA GEMM (+bias), bf16 out. grid (M/128, N/64).
// Kept only for the tiny Wot GEMM (768x768, K=384).
// ---------------------------------------------------------------------------
template <int BIAS>
__global__ __launch_bounds__(256) void gemm_n64_kernel(
    const ushort* __restrict__ A, const ushort* __restrict__ Bt,
    const float* __restrict__ bias, ushort* __restrict__ C,
    int M, int N, int K) {
  __shared__ __align__(16) ushort Als[128 * 32];
  __shared__ __align__(16) ushort Bls[64 * 32];
  const int tid  = threadIdx.x;
  const int lane = tid & 63;
  const int quad = lane >> 4, l16 = lane & 15;
  const int wu   = __builtin_amdgcn_readfirstlane(tid >> 6);
  const int row0 = blockIdx.x * 128, col0 = blockIdx.y * 64;

  floatx4 acc[2][4] = {};

  for (int k0 = 0; k0 < K; k0 += 32) {
    __syncthreads();
#pragma unroll
    for (int is = 0; is < 2; is++) {
      int c = is * 256 + wu * 64 + lane;
      int m = c >> 2, kk = (c & 3) << 3;
      const ushort* ga = A + (size_t)(row0 + m) * K + (k0 + kk);
      ushort* la = Als + (size_t)(is * 256 + wu * 64) * 8;
      __builtin_amdgcn_global_load_lds(
          (const __attribute__((address_space(1))) void*)ga,
          (__attribute__((address_space(3))) void*)la, 16, 0, 0);
    }
    {
      int c = wu * 64 + lane;
      int m = c >> 2, kk = (c & 3) << 3;
      const ushort* gb = Bt + (size_t)(col0 + m) * K + (k0 + kk);
      ushort* lb = Bls + (size_t)(wu * 64) * 8;
      __builtin_amdgcn_global_load_lds(
          (const __attribute__((address_space(1))) void*)gb,
          (__attribute__((address_space(3))) void*)lb, 16, 0, 0);
    }
    __syncthreads();

    short8 af[2], bf[4];
#pragma unroll
    for (int mt = 0; mt < 2; mt++)
      af[mt] = *(const short8*)(Als + ((wu * 32 + mt * 16 + l16) * 32 + quad * 8));
#pragma unroll
    for (int nt = 0; nt < 4; nt++)
      bf[nt] = *(const short8*)(Bls + ((nt * 16 + l16) * 32 + quad * 8));
#pragma unroll
    for (int mt = 0; mt < 2; mt++)
#pragma unroll
      for (int nt = 0; nt < 4; nt++)
        acc[mt][nt] = __builtin_amdgcn_mfma_f32_16x16x32_bf16(
            af[mt], bf[nt], acc[mt][nt], 0, 0, 0);
  }

#pragma unroll
  for (int mt = 0; mt < 2; mt++) {
#pragma unroll
    for (int nt = 0; nt < 4; nt++) {
      int colg = col0 + nt * 16 + l16;
      float bv_ = BIAS ? bias[colg] : 0.f;
      int rowg0 = row0 + wu * 32 + mt * 16 + quad * 4;
#pragma unroll
      for (int r = 0; r < 4; r++)
        C[(size_t)(rowg0 + r) * N + colg] = f2b(acc[mt][nt][r] + bv_);
    }
  }
}

// ---------------------------------------------------------------------------
// MFMA flash attention v11 (R5-verified). UNCHANGED.
// ---------------------------------------------------------------------------
__global__ __launch_bounds__(256, 3) void attn_mfma_kernel(
    const ushort* __restrict__ Q, const ushort* __restrict__ K,
    const ushort* __restrict__ Vt, const float* __restrict__ mask,
    ushort* __restrict__ O) {
  // bijective decode: bid = (slot*8 + qt)*8 + xcd ; grp = slot*8 + xcd
  const int bid  = blockIdx.x;          // 768 blocks
  const int xcd  = bid & 7;
  const int rest = bid >> 3;            // 0..95
  const int qt   = rest & 7;
  const int grp  = (rest >> 3) * 8 + xcd;   // 0..95, grp%8 == xcd
  const int h = grp % 12, b = grp / 12;

  const int tid = threadIdx.x;
  const int lane = tid & 63;
  const int quad = lane >> 4, l16 = lane & 15;
  const int wu = __builtin_amdgcn_readfirstlane(tid >> 6);
  const int qrow0 = qt * 128 + wu * 32;

  __shared__ __align__(16) ushort Ks[2][64 * 64];   // [buf][key][dh], swz slots
  __shared__ __align__(16) ushort Vts[2][64 * 64];  // [buf][dh][key], swz slots
  __shared__ __align__(16) float Msk[SEQ];          // whole mask row

  // one-time mask row preload (1024 floats, one float4/thread)
  *(float4*)(Msk + tid * 4) = *(const float4*)(mask + (size_t)b * SEQ + tid * 4);

  short8 qf[2][2];
#pragma unroll
  for (int rt = 0; rt < 2; rt++) {
    const ushort* qp = Q + ((size_t)(b * SEQ + qrow0 + rt * 16 + l16)) * D_MODEL
                     + h * DHEAD + quad * 8;
    qf[rt][0] = *(const short8*)qp;
    qf[rt][1] = *(const short8*)(qp + 32);
  }

  // staging decomposition: 64 rows x 8 slots, 2 rounds of 32 rows
  const int j0 = tid >> 3, ck = tid & 7;
  const ushort* Kg = K + ((size_t)(b * SEQ + j0)) * D_MODEL + h * DHEAD + ck * 8;
  const ushort* Vg = Vt + ((size_t)(h * DHEAD + j0)) * BM + b * SEQ + ck * 8;
  const int kloff = j0 * 64 + ((ck ^ (j0 & 7)) << 3);   // (row&7) const over p

  // prologue: chunk 0 -> regs -> buf0; then issue chunk-1 loads
  short8 kst[2], vst[2];
#pragma unroll
  for (int p = 0; p < 2; p++) {
    kst[p] = *(const short8*)(Kg + (size_t)(p * 32) * D_MODEL);
    vst[p] = *(const short8*)(Vg + (size_t)p * (32 * BM));
  }
#pragma unroll
  for (int p = 0; p < 2; p++) {
    *(short8*)(&Ks[0][0] + kloff + p * (32 * 64)) = kst[p];
    *(short8*)(&Vts[0][0] + kloff + p * (32 * 64)) = vst[p];
  }
#pragma unroll
  for (int p = 0; p < 2; p++) {
    kst[p] = *(const short8*)(Kg + (size_t)(64 + p * 32) * D_MODEL);
    vst[p] = *(const short8*)(Vg + 64 + (size_t)p * (32 * BM));
  }
  asm volatile("s_waitcnt lgkmcnt(0)" ::: "memory");
  __builtin_amdgcn_s_barrier();
  asm volatile("" ::: "memory");

  float lsum[2] = {0.f, 0.f};
  floatx4 o_acc[2][4] = {};

  for (int n0 = 0; n0 < SEQ; n0 += 64) {
    const int cur = (n0 >> 6) & 1;

    // (1) write staged regs (chunk i+1) -> buf[cur^1]
    if (n0 + 64 < SEQ) {
#pragma unroll
      for (int p = 0; p < 2; p++) {
        *(short8*)(&Ks[cur ^ 1][0] + kloff + p * (32 * 64)) = kst[p];
        *(short8*)(&Vts[cur ^ 1][0] + kloff + p * (32 * 64)) = vst[p];
      }
      // (2) issue chunk i+2 global loads (land during compute below)
      if (n0 + 128 < SEQ) {
#pragma unroll
        for (int p = 0; p < 2; p++) {
          kst[p] = *(const short8*)(Kg + (size_t)(n0 + 128 + p * 32) * D_MODEL);
          vst[p] = *(const short8*)(Vg + (n0 + 128) + (size_t)p * (32 * BM));
        }
      }
    }

    // (3) compute chunk i from buf[cur]
    __builtin_amdgcn_s_setprio(1);
    unsigned UA[2][4], UB[2][4];
#pragma unroll
    for (int ct = 0; ct < 4; ct++) {
      int krow = ct * 16 + l16;
      int sa = (quad ^ (l16 & 7)) << 3;                 // swizzled 16B slot
      const ushort* kbp = &Ks[cur][0] + krow * 64;
      short8 ka = *(const short8*)(kbp + sa);           // K[krow][quad*8..]
      short8 kb = *(const short8*)(kbp + (sa ^ 32));    // K[krow][32+quad*8..]
      float4 mk = *(const float4*)(Msk + n0 + ct * 16 + quad * 4);
#pragma unroll
      for (int rt = 0; rt < 2; rt++) {
        floatx4 st = {};
        st = __builtin_amdgcn_mfma_f32_16x16x32_bf16(ka, qf[rt][0], st, 0, 0, 0);
        st = __builtin_amdgcn_mfma_f32_16x16x32_bf16(kb, qf[rt][1], st, 0, 0, 0);
        float e0 = __expf(st[0] + mk.x);     // Q pre-scaled by 1/sqrt(dh)
        float e1 = __expf(st[1] + mk.y);
        float e2 = __expf(st[2] + mk.z);
        float e3 = __expf(st[3] + mk.w);
        lsum[rt] += (e0 + e1) + (e2 + e3);
        UA[rt][ct] = pk2(e0, e1);            // keys quad*4+0,1 (query l16)
        UB[rt][ct] = pk2(e2, e3);            // keys quad*4+2,3
      }
    }

#pragma unroll
    for (int kk = 0; kk < 2; kk++) {
      short8 pa[2];
#pragma unroll
      for (int rt = 0; rt < 2; rt++) {
        // in-register P transpose: dest quad q, dword w <- keys q*8+2w,+2w+1
        unsigned a0 = UA[rt][2 * kk], a2 = UA[rt][2 * kk + 1];
        unsigned b1 = UB[rt][2 * kk], b3 = UB[rt][2 * kk + 1];
        asm("v_permlane32_swap_b32 %0, %1" : "+v"(a0), "+v"(a2));
        asm("v_permlane16_swap_b32 %0, %1" : "+v"(a0), "+v"(a2));
        asm("v_permlane32_swap_b32 %0, %1" : "+v"(b1), "+v"(b3));
        asm("v_permlane16_swap_b32 %0, %1" : "+v"(b1), "+v"(b3));
        int4 t;
        t.x = (int)a0;   // keys q*8+0,1
        t.y = (int)b1;   // keys q*8+2,3
        t.z = (int)a2;   // keys q*8+4,5
        t.w = (int)b3;   // keys q*8+6,7
        pa[rt] = *(short8*)&t;
      }
#pragma unroll
      for (int dt = 0; dt < 4; dt++) {
        int vr = dt * 16 + l16;
        short8 vb = *(const short8*)(&Vts[cur][0] + vr * 64
                                     + (((kk * 4 + quad) ^ (l16 & 7)) << 3));
#pragma unroll
        for (int rt = 0; rt < 2; rt++)
          o_acc[rt][dt] = __builtin_amdgcn_mfma_f32_16x16x32_bf16(
              pa[rt], vb, o_acc[rt][dt], 0, 0, 0);
      }
    }
    __builtin_amdgcn_s_setprio(0);

    // (4) one barrier per chunk (drain own ds_writes first)
    if (n0 + 64 < SEQ) {
      asm volatile("s_waitcnt lgkmcnt(0)" ::: "memory");
      __builtin_amdgcn_s_barrier();
      asm volatile("" ::: "memory");
    }
  }

#pragma unroll
  for (int rt = 0; rt < 2; rt++) {
    float l = lsum[rt];
    l += __shfl_xor(l, 16);
    l += __shfl_xor(l, 32);
    float inv = 1.f / l;
    int lanebase = lane & 48;
#pragma unroll
    for (int rr = 0; rr < 4; rr++) {
      int iv = __builtin_amdgcn_ds_bpermute((lanebase | (quad * 4 + rr)) << 2,
                                            __float_as_int(inv));
      float invr = __int_as_float(iv);
      size_t rowg = (size_t)(b * SEQ + qrow0 + rt * 16 + quad * 4 + rr);
#pragma unroll
      for (int dt = 0; dt < 4; dt++)
        O[rowg * D_MODEL + h * DHEAD + dt * 16 + l16] = f2b(o_acc[rt][dt][rr] * invr);
    }
  }
}

// ---------------------------------------------------------------------------
// out = LayerNorm(Ain + Bin)*g + bt. Bin bf16. Ain fp32 or bf16.
// ---------------------------------------------------------------------------
template <int AIN_BF16, int OUT_FP32, int OUT_BF16>
__global__ __launch_bounds__(256) void add_ln_kernel(
    const float* __restrict__ Ainf, const ushort* __restrict__ Ainb,
    const ushort* __restrict__ Binb,
    const float* __restrict__ g, const float* __restrict__ bt,
    float* __restrict__ outf, ushort* __restrict__ outb) {
  const int row = blockIdx.x, tid = threadIdx.x;
  __shared__ float red[4];
  float v[3];
  float s = 0.f;
#pragma unroll
  for (int u = 0; u < 3; u++) {
    int c = tid + u * 256;
    float a = AIN_BF16 ? b2f(Ainb[(size_t)row * 768 + c]) : Ainf[(size_t)row * 768 + c];
    v[u] = a + b2f(Binb[(size_t)row * 768 + c]);
    s += v[u];
  }
#pragma unroll
  for (int off = 32; off > 0; off >>= 1) s += __shfl_down(s, off);
  if ((tid & 63) == 0) red[tid >> 6] = s;
  __syncthreads();
  float mu = (red[0] + red[1] + red[2] + red[3]) * (1.f / 768.f);
  float s2 = 0.f;
#pragma unroll
  for (int u = 0; u < 3; u++) { float d = v[u] - mu; s2 += d * d; }
#pragma unroll
  for (int off = 32; off > 0; off >>= 1) s2 += __shfl_down(s2, off);
  __syncthreads();
  if ((tid & 63) == 0) red[tid >> 6] = s2;
  __syncthreads();
  float var = (red[0] + red[1] + red[2] + red[3]) * (1.f / 768.f);
  float inv = rsqrtf(var + 1e-12f);
#pragma unroll
  for (int u = 0; u < 3; u++) {
    int c = tid + u * 256;
    float r = g[c] * (v[u] - mu) * inv + bt[c];
    if (OUT_FP32) outf[(size_t)row * 768 + c] = r;
    if (OUT_BF16) outb[(size_t)row * 768 + c] = f2b(r);
  }
}

// ---------------------------------------------------------------------------
extern "C" void kernel_launch(void* const* d_in, const int* in_sizes, int n_in,
                              void* d_out, int out_size, void* d_ws, size_t ws_size,
                              hipStream_t stream) {
  const float* x    = (const float*)d_in[0];
  const float* mask = (const float*)d_in[1];
  const float* Pq   = (const float*)d_in[2];
  const float* Vq   = (const float*)d_in[3];
  const float* bq   = (const float*)d_in[4];
  const float* Pk   = (const float*)d_in[5];
  const float* Vk   = (const float*)d_in[6];
  const float* bk   = (const float*)d_in[7];
  const float* Pv   = (const float*)d_in[8];
  const float* Vv   = (const float*)d_in[9];
  const float* bv   = (const float*)d_in[10];
  const float* Uo   = (const float*)d_in[11];
  const float* Vo   = (const float*)d_in[12];
  const float* bo   = (const float*)d_in[13];
  const float* U1   = (const float*)d_in[14];
  const float* V1   = (const float*)d_in[15];
  const float* b1   = (const float*)d_in[16];
  const float* U2   = (const float*)d_in[17];
  const float* V2   = (const float*)d_in[18];
  const float* b2   = (const float*)d_in[19];
  const float* g1   = (const float*)d_in[20];
  const float* be1  = (const float*)d_in[21];
  const float* g2   = (const float*)d_in[22];
  const float* be2  = (const float*)d_in[23];

  // --- workspace carve (bytes, 256-aligned) ---
  char* w = (char*)d_ws;
  auto alloc = [&](size_t bytes) -> char* {
    char* p = w; w += (bytes + 255) & ~(size_t)255; return p;
  };
  ushort* Wqkvt  = (ushort*)alloc((size_t)2304 * 768 * 2);
  float*  ball   = (float*)alloc(2304 * 4);
  ushort* VoT    = (ushort*)alloc(768 * 384 * 2);   // Vo^T bf16 (A operand)
  ushort* Uob    = (ushort*)alloc(768 * 384 * 2);   // Uo bf16 (Bt operand)
  ushort* Wot    = (ushort*)alloc(768 * 768 * 2);   // Vo^T @ Uo^T = Wo^T
  ushort* U1t    = (ushort*)alloc(384 * 768 * 2);
  ushort* V1t    = (ushort*)alloc((size_t)3072 * 384 * 2);
  ushort* U2t    = (ushort*)alloc((size_t)384 * 3072 * 2);
  ushort* V2t    = (ushort*)alloc(768 * 384 * 2);
  ushort* Qb     = (ushort*)alloc((size_t)BM * 768 * 2);
  ushort* Kb     = (ushort*)alloc((size_t)BM * 768 * 2);
  ushort* Vtb    = (ushort*)alloc((size_t)768 * BM * 2);
  ushort* attnb  = (ushort*)alloc((size_t)BM * 768 * 2);
  ushort* mtb    = (ushort*)alloc((size_t)BM * 384 * 2);   // mid / t2
  ushort* y1b    = (ushort*)alloc((size_t)BM * 768 * 2);
  ushort* x1b    = (ushort*)alloc((size_t)BM * 768 * 2);
  float*  part   = (float*)alloc((size_t)4 * BM * 384 * 4);
  // aliases (dead-buffer reuse)
  ushort* hiddenb = Qb;             // Qb..attnb (50.3 MB) dead after y1 GEMM
  ushort* y2b     = y1b;            // y1b dead after LN1
  float*  outp    = (float*)d_out;

  // 1) weight prep (no x f2b: fused into the QKV GEMM's A-staging)
  combine_qkv_kernel<<<dim3(2304, 3), 256, 0, stream>>>(Pq, Vq, Pk, Vk, Pv, Vv, Wqkvt);
  concat_bias_kernel<<<9, 256, 0, stream>>>(bq, bk, bv, ball);
  prep_weights_kernel<<<3456, 256, 0, stream>>>(U1, V1, U2, V2, Vo, Uo,
                                                U1t, V1t, U2t, V2t, VoT, Uob);
  // Wot[n][d] = sum_r Vo^T[n][r] * Uo[d][r]  (= Wo[d][n], the Bt operand for y1)
  gemm_n64_kernel<0><<<dim3(6, 12), 256, 0, stream>>>(VoT, Uob, nullptr, Wot, 768, 768, 384);

  // 2) fused QKV = x @ [Wq|Wk|Wv] + bias  (A read fp32, packed in staging)
  gemm_mfma_kernel<3, 1, 0, 1><<<dim3(64, 18), 256, 0, stream>>>(
      (const ushort*)x, Wqkvt, ball, Qb, Kb, Vtb, BM, 2304, 768);

  // 3) MFMA flash attention (dbuf 1-barrier pipeline) -> bf16 (B*M, 768)
  attn_mfma_kernel<<<dim3(768), 256, 0, stream>>>(Qb, Kb, Vtb, mask, attnb);

  // 4) attn out-projection: y1 = attn @ Wo + bo  (128^2 piped GEMM)
  gemm_mfma_kernel<1, 1, 0><<<dim3(64, 6), 256, 0, stream>>>(
      attnb, Wot, bo, y1b, nullptr, nullptr, BM, 768, 768);
  add_ln_kernel<0, 0, 1><<<BM, 256, 0, stream>>>(x, nullptr, y1b, g1, be1, nullptr, x1b);

  // 5) FFN (low rank) with fast GELU
  gemm_mfma_kernel<1, 0, 0><<<dim3(64, 3), 256, 0, stream>>>(
      x1b, U1t, nullptr, mtb, nullptr, nullptr, BM, 384, 768);
  gemm_mfma_kernel<1, 1, 1><<<dim3(64, 24), 256, 0, stream>>>(
      mtb, V1t, b1, hiddenb, nullptr, nullptr, BM, 3072, 384);
  //    t2 = hidden @ U2 (K=3072): piped splitk S=2
  gemm_piped_splitk_kernel<<<dim3(64, 3, 2), 256, 0, stream>>>(
      hiddenb, U2t, part, BM, 384, 3072, 1536);
  reduce_splitk_kernel<<<(BM * 384) / 1024, 256, 0, stream>>>(part, mtb, BM * 384, 2);
  gemm_mfma_kernel<1, 1, 0><<<dim3(64, 6), 256, 0, stream>>>(
      mtb, V2t, b2, y2b, nullptr, nullptr, BM, 768, 384);

  // 6) residual + LN2 -> output (fp32)
  add_ln_kernel<1, 1, 0><<<BM, 256, 0, stream>>>(nullptr, x1b, y2b, g2, be2, outp, nullptr);
}

// Round 10
// 388.302 us; speedup vs baseline: 1.0918x; 1.0027x over previous
//
#include <hip/hip_runtime.h>
#include <cstddef>

// Problem constants
#define D_MODEL 768
#define NHEAD   12
#define DHEAD   64
#define RANK    32
#define SEQ     1024
#define BATCH   8
#define BM      8192      // BATCH*SEQ

typedef __attribute__((ext_vector_type(8))) short short8;
typedef __attribute__((ext_vector_type(4))) float floatx4;

__device__ inline ushort f2b(float f) {           // fp32 -> bf16 RNE
  union { float f; unsigned u; } v; v.f = f;
  unsigned r = v.u + 0x7fffu + ((v.u >> 16) & 1u);
  return (ushort)(r >> 16);
}
__device__ inline float b2f(ushort h) {
  union { unsigned u; float f; } v; v.u = ((unsigned)h) << 16;
  return v.f;
}
// pack two fp32 -> bf16x2 dword
__device__ inline unsigned pk2(float a, float b) {
  return ((__float_as_uint(b) + 0x8000u) & 0xffff0000u) |
         ((__float_as_uint(a) + 0x8000u) >> 16);
}
// tanh-form GELU with fast exp (max |err vs erf-GELU| ~1e-3)
__device__ inline float fast_gelu(float x) {
  float z = 0.79788456080286536f * (x + 0.044715f * x * x * x);
  float e = __expf(2.f * z);
  float t = 1.f - 2.f / (e + 1.f);
  return 0.5f * x * (1.f + t);
}

// ---------------------------------------------------------------------------
// R10: reinstated (R9's fp32-fused QKV A-staging regressed QKV 50->62us:
// fp32 A re-read by 18 col-block groups through L2 + 2x VMEM issue on the
// staging critical path. Separate f2b round-trip is net ~4us cheaper.)
// ---------------------------------------------------------------------------
__global__ __launch_bounds__(256) void f2b_kernel(
    const float* __restrict__ in, ushort* __restrict__ out, int n) {
  int i = (blockIdx.x * 256 + threadIdx.x) * 4;
  if (i >= n) return;
  float4 v = *(const float4*)(in + i);
  ushort4 o;
  o.x = f2b(v.x); o.y = f2b(v.y); o.z = f2b(v.z); o.w = f2b(v.w);
  *(ushort4*)(out + i) = o;
}

// ---------------------------------------------------------------------------
// All three QKV low-rank combines in one launch (grid.y selects q/k/v):
// Wt[y][c=h*64+k][d] = sum_r P[h,d,r] * Vw[h,r,k]
// ---------------------------------------------------------------------------
__global__ __launch_bounds__(256) void combine_qkv_kernel(
    const float* __restrict__ Pq, const float* __restrict__ Vq,
    const float* __restrict__ Pk, const float* __restrict__ Vk,
    const float* __restrict__ Pv, const float* __restrict__ Vv,
    ushort* __restrict__ Wt) {
  int which = blockIdx.y;
  const float* P  = which == 0 ? Pq : (which == 1 ? Pk : Pv);
  const float* Vw = which == 0 ? Vq : (which == 1 ? Vk : Vv);
  ushort* W = Wt + (size_t)which * D_MODEL * D_MODEL;
  int idx = blockIdx.x * 256 + threadIdx.x;
  if (idx >= D_MODEL * NHEAD * DHEAD) return;
  int c = idx / D_MODEL;
  int d = idx - c * D_MODEL;
  int h = c >> 6, k = c & 63;
  const float* p = P + ((size_t)h * D_MODEL + d) * RANK;
  const float* v = Vw + (size_t)h * RANK * DHEAD + k;
  float s = 0.f;
#pragma unroll
  for (int r = 0; r < RANK; r++) s += p[r] * v[(size_t)r * DHEAD];
  W[(size_t)c * D_MODEL + d] = f2b(s);
}

__global__ __launch_bounds__(256) void concat_bias_kernel(
    const float* __restrict__ bq, const float* __restrict__ bk,
    const float* __restrict__ bv, float* __restrict__ out) {
  int i = blockIdx.x * 256 + threadIdx.x;
  if (i >= 2304) return;
  out[i] = (i < 768) ? bq[i] : (i < 1536 ? bk[i - 768] : bv[i - 1536]);
}

// ---------------------------------------------------------------------------
// Six weight preps in one launch (block-range decode):
// transposes (fp32 (R,C) -> bf16 (C,R)): U1(768,384) V1(384,3072)
//   U2(3072,384) V2(384,768) Vo(384,768)
// plus straight f2b copy of Uo (768x384) for the Wot GEMM's Bt operand.
// ---------------------------------------------------------------------------
__global__ __launch_bounds__(256) void prep_weights_kernel(
    const float* __restrict__ U1, const float* __restrict__ V1,
    const float* __restrict__ U2, const float* __restrict__ V2,
    const float* __restrict__ Vo, const float* __restrict__ Uo,
    ushort* __restrict__ U1t, ushort* __restrict__ V1t,
    ushort* __restrict__ U2t, ushort* __restrict__ V2t,
    ushort* __restrict__ VoT, ushort* __restrict__ Uob) {
  __shared__ float t[32][33];
  int blk = blockIdx.x;
  if (blk >= 3168) {                 // Uo f2b copy: 288 blocks x 1024 elems
    int i = (blk - 3168) * 1024 + threadIdx.x * 4;
    float4 v = *(const float4*)(Uo + i);
    ushort4 o;
    o.x = f2b(v.x); o.y = f2b(v.y); o.z = f2b(v.z); o.w = f2b(v.w);
    *(ushort4*)(Uob + i) = o;
    return;
  }
  const float* in; ushort* out; int R, C, bx, by;
  if (blk < 288)       { in = U1; out = U1t; R = 768;  C = 384;  int i = blk;        bx = i % 12; by = i / 12; }
  else if (blk < 1440) { in = V1; out = V1t; R = 384;  C = 3072; int i = blk - 288;  bx = i % 96; by = i / 96; }
  else if (blk < 2592) { in = U2; out = U2t; R = 3072; C = 384;  int i = blk - 1440; bx = i % 12; by = i / 12; }
  else if (blk < 2880) { in = V2; out = V2t; R = 384;  C = 768;  int i = blk - 2592; bx = i % 24; by = i / 24; }
  else                 { in = Vo; out = VoT; R = 384;  C = 768;  int i = blk - 2880; bx = i % 24; by = i / 24; }
  int c0 = bx * 32, r0 = by * 32;
  int lx = threadIdx.x & 31, ly = threadIdx.x >> 5;
#pragma unroll
  for (int i = 0; i < 32; i += 8)
    t[ly + i][lx] = in[(size_t)(r0 + ly + i) * C + c0 + lx];
  __syncthreads();
#pragma unroll
  for (int i = 0; i < 32; i += 8)
    out[(size_t)(c0 + ly + i) * R + r0 + lx] = f2b(t[lx][ly + i]);
}

// ---------------------------------------------------------------------------
// bf16 MFMA GEMM v2 (R7-verified structure): 128^2, BK=64, reg-staged dbuf,
// ONE raw barrier per K-step, lgkmcnt-only drain (VMEM for step s+2 stays in
// flight across the barrier), XOR-swizzled 16B slots both sides, setprio
// around the MFMA cluster.
// OUTMODE: 1 bf16 (M,N); 3 fused QKV (Q pre-scaled 1/8; V transposed out).
// grid (M/128, N/128): x = M-block (R6 XCD A-reuse).
// ---------------------------------------------------------------------------
template <int OUTMODE, int BIAS, int GELU>
__global__ __launch_bounds__(256, 2) void gemm_mfma_kernel(
    const ushort* __restrict__ A, const ushort* __restrict__ Bt,
    const float* __restrict__ bias, void* __restrict__ C,
    void* __restrict__ C2, void* __restrict__ C3,
    int M, int N, int K) {
  __shared__ __align__(16) ushort Als[2][128 * 64];
  __shared__ __align__(16) ushort Bls[2][128 * 64];
  const int tid  = threadIdx.x;
  const int lane = tid & 63;
  const int quad = lane >> 4, l16 = lane & 15;
  const int wu   = __builtin_amdgcn_readfirstlane(tid >> 6);
  const int wrow = (wu >> 1) * 64, wcol = (wu & 1) * 64;
  const int row0 = blockIdx.x * 128, col0 = blockIdx.y * 128;

  const int r_ = tid >> 3, sl_ = tid & 7;
  const ushort* Ag = A + (size_t)(row0 + r_) * K + sl_ * 8;
  const ushort* Bg = Bt + (size_t)(col0 + r_) * K + sl_ * 8;
  const int loff = r_ * 64 + ((sl_ ^ (r_ & 7)) << 3);

  const int nsteps = K >> 6;
  short8 ast[4], bst[4];

  // prologue: step-0 tile -> regs -> buf0; then issue step-1 loads
#pragma unroll
  for (int p = 0; p < 4; p++) {
    ast[p] = *(const short8*)(Ag + (size_t)(32 * p) * K);
    bst[p] = *(const short8*)(Bg + (size_t)(32 * p) * K);
  }
#pragma unroll
  for (int p = 0; p < 4; p++) {
    *(short8*)(&Als[0][0] + loff + p * (32 * 64)) = ast[p];
    *(short8*)(&Bls[0][0] + loff + p * (32 * 64)) = bst[p];
  }
#pragma unroll
  for (int p = 0; p < 4; p++) {
    ast[p] = *(const short8*)(Ag + (size_t)(32 * p) * K + 64);
    bst[p] = *(const short8*)(Bg + (size_t)(32 * p) * K + 64);
  }
  asm volatile("s_waitcnt lgkmcnt(0)" ::: "memory");
  __builtin_amdgcn_s_barrier();
  asm volatile("" ::: "memory");

  floatx4 acc[4][4] = {};

  for (int s = 0; s < nsteps; s++) {
    const int cur = s & 1;

    if (s + 1 < nsteps) {
#pragma unroll
      for (int p = 0; p < 4; p++) {
        *(short8*)(&Als[cur ^ 1][0] + loff + p * (32 * 64)) = ast[p];
        *(short8*)(&Bls[cur ^ 1][0] + loff + p * (32 * 64)) = bst[p];
      }
      if (s + 2 < nsteps) {
        const int ko = (s + 2) * 64;
#pragma unroll
        for (int p = 0; p < 4; p++) {
          ast[p] = *(const short8*)(Ag + (size_t)(32 * p) * K + ko);
          bst[p] = *(const short8*)(Bg + (size_t)(32 * p) * K + ko);
        }
      }
    }

    __builtin_amdgcn_s_setprio(1);
#pragma unroll
    for (int kk = 0; kk < 2; kk++) {
      short8 af[4], bf[4];
#pragma unroll
      for (int mt = 0; mt < 4; mt++) {
        int row = wrow + mt * 16 + l16;
        af[mt] = *(const short8*)(&Als[cur][0] + row * 64
                                  + (((kk * 4 + quad) ^ (l16 & 7)) << 3));
      }
#pragma unroll
      for (int nt = 0; nt < 4; nt++) {
        int row = wcol + nt * 16 + l16;
        bf[nt] = *(const short8*)(&Bls[cur][0] + row * 64
                                  + (((kk * 4 + quad) ^ (l16 & 7)) << 3));
      }
#pragma unroll
      for (int mt = 0; mt < 4; mt++)
#pragma unroll
        for (int nt = 0; nt < 4; nt++)
          acc[mt][nt] = __builtin_amdgcn_mfma_f32_16x16x32_bf16(
              af[mt], bf[nt], acc[mt][nt], 0, 0, 0);
    }
    __builtin_amdgcn_s_setprio(0);

    if (s + 1 < nsteps) {
      asm volatile("s_waitcnt lgkmcnt(0)" ::: "memory");
      __builtin_amdgcn_s_barrier();
      asm volatile("" ::: "memory");
    }
  }

#pragma unroll
  for (int mt = 0; mt < 4; mt++) {
#pragma unroll
    for (int nt = 0; nt < 4; nt++) {
      int colg = col0 + wcol + nt * 16 + l16;
      float bv_ = BIAS ? bias[colg] : 0.f;
      float v4[4];
#pragma unroll
      for (int r = 0; r < 4; r++) {
        float v = acc[mt][nt][r] + bv_;
        if (GELU) v = fast_gelu(v);
        v4[r] = v;
      }
      int rowg0 = row0 + wrow + mt * 16 + quad * 4;
      if (OUTMODE == 3) {
        int seg = col0 / 768;
        int cl = colg - seg * 768;
        if (seg == 2) {
          ushort4 o;
          o.x = f2b(v4[0]); o.y = f2b(v4[1]); o.z = f2b(v4[2]); o.w = f2b(v4[3]);
          *(ushort4*)((ushort*)C3 + (size_t)cl * BM + rowg0) = o;
        } else {
          ushort* dst = (seg == 0) ? (ushort*)C : (ushort*)C2;
          float sc = (seg == 0) ? 0.125f : 1.f;   // fold 1/sqrt(64) into Q
#pragma unroll
          for (int r = 0; r < 4; r++)
            dst[(size_t)(rowg0 + r) * D_MODEL + cl] = f2b(v4[r] * sc);
        }
      } else {
#pragma unroll
        for (int r = 0; r < 4; r++)
          ((ushort*)C)[(size_t)(rowg0 + r) * N + colg] = f2b(v4[r]);
      }
    }
  }
}

// ---------------------------------------------------------------------------
// Piped split-K bf16 MFMA GEMM (R9-verified): same R7 pipeline, K-range
// [kbase, kbase+Kper), fp32 partial output. grid (M/128, N/128, S).
// ---------------------------------------------------------------------------
__global__ __launch_bounds__(256, 2) void gemm_piped_splitk_kernel(
    const ushort* __restrict__ A, const ushort* __restrict__ Bt,
    float* __restrict__ Cpart, int M, int N, int Ktot, int Kper) {
  __shared__ __align__(16) ushort Als[2][128 * 64];
  __shared__ __align__(16) ushort Bls[2][128 * 64];
  const int tid  = threadIdx.x;
  const int lane = tid & 63;
  const int quad = lane >> 4, l16 = lane & 15;
  const int wu   = __builtin_amdgcn_readfirstlane(tid >> 6);
  const int wrow = (wu >> 1) * 64, wcol = (wu & 1) * 64;
  const int row0 = blockIdx.x * 128, col0 = blockIdx.y * 128;
  const int kbase = blockIdx.z * Kper;
  float* Cz = Cpart + (size_t)blockIdx.z * M * N;

  const int r_ = tid >> 3, sl_ = tid & 7;
  const ushort* Ag = A + (size_t)(row0 + r_) * Ktot + kbase + sl_ * 8;
  const ushort* Bg = Bt + (size_t)(col0 + r_) * Ktot + kbase + sl_ * 8;
  const int loff = r_ * 64 + ((sl_ ^ (r_ & 7)) << 3);

  const int nsteps = Kper >> 6;
  short8 ast[4], bst[4];

#pragma unroll
  for (int p = 0; p < 4; p++) {
    ast[p] = *(const short8*)(Ag + (size_t)(32 * p) * Ktot);
    bst[p] = *(const short8*)(Bg + (size_t)(32 * p) * Ktot);
  }
#pragma unroll
  for (int p = 0; p < 4; p++) {
    *(short8*)(&Als[0][0] + loff + p * (32 * 64)) = ast[p];
    *(short8*)(&Bls[0][0] + loff + p * (32 * 64)) = bst[p];
  }
#pragma unroll
  for (int p = 0; p < 4; p++) {
    ast[p] = *(const short8*)(Ag + (size_t)(32 * p) * Ktot + 64);
    bst[p] = *(const short8*)(Bg + (size_t)(32 * p) * Ktot + 64);
  }
  asm volatile("s_waitcnt lgkmcnt(0)" ::: "memory");
  __builtin_amdgcn_s_barrier();
  asm volatile("" ::: "memory");

  floatx4 acc[4][4] = {};

  for (int s = 0; s < nsteps; s++) {
    const int cur = s & 1;

    if (s + 1 < nsteps) {
#pragma unroll
      for (int p = 0; p < 4; p++) {
        *(short8*)(&Als[cur ^ 1][0] + loff + p * (32 * 64)) = ast[p];
        *(short8*)(&Bls[cur ^ 1][0] + loff + p * (32 * 64)) = bst[p];
      }
      if (s + 2 < nsteps) {
        const int ko = (s + 2) * 64;
#pragma unroll
        for (int p = 0; p < 4; p++) {
          ast[p] = *(const short8*)(Ag + (size_t)(32 * p) * Ktot + ko);
          bst[p] = *(const short8*)(Bg + (size_t)(32 * p) * Ktot + ko);
        }
      }
    }

    __builtin_amdgcn_s_setprio(1);
#pragma unroll
    for (int kk = 0; kk < 2; kk++) {
      short8 af[4], bf[4];
#pragma unroll
      for (int mt = 0; mt < 4; mt++) {
        int row = wrow + mt * 16 + l16;
        af[mt] = *(const short8*)(&Als[cur][0] + row * 64
                                  + (((kk * 4 + quad) ^ (l16 & 7)) << 3));
      }
#pragma unroll
      for (int nt = 0; nt < 4; nt++) {
        int row = wcol + nt * 16 + l16;
        bf[nt] = *(const short8*)(&Bls[cur][0] + row * 64
                                  + (((kk * 4 + quad) ^ (l16 & 7)) << 3));
      }
#pragma unroll
      for (int mt = 0; mt < 4; mt++)
#pragma unroll
        for (int nt = 0; nt < 4; nt++)
          acc[mt][nt] = __builtin_amdgcn_mfma_f32_16x16x32_bf16(
              af[mt], bf[nt], acc[mt][nt], 0, 0, 0);
    }
    __builtin_amdgcn_s_setprio(0);

    if (s + 1 < nsteps) {
      asm volatile("s_waitcnt lgkmcnt(0)" ::: "memory");
      __builtin_amdgcn_s_barrier();
      asm volatile("" ::: "memory");
    }
  }

#pragma unroll
  for (int mt = 0; mt < 4; mt++)
#pragma unroll
    for (int nt = 0; nt < 4; nt++) {
      int colg = col0 + wcol + nt * 16 + l16;
      int rowg0 = row0 + wrow + mt * 16 + quad * 4;
#pragma unroll
      for (int r = 0; r < 4; r++)
        Cz[(size_t)(rowg0 + r) * N + colg] = acc[mt][nt][r];
    }
}

__global__ __launch_bounds__(256) void reduce_splitk_kernel(
    const float* __restrict__ part, ushort* __restrict__ out, int n, int S) {
  int i = (blockIdx.x * 256 + threadIdx.x) * 4;
  if (i >= n) return;
  float4 a = *(const float4*)(part + i);
  for (int s = 1; s < S; s++) {
    float4 b = *(const float4*)(part + (size_t)s * n + i);
    a.x += b.x; a.y += b.y; a.z += b.z; a.w += b.w;
  }
  ushort4 o;
  o.x = f2b(a.x); o.y = f2b(a.y); o.z = f2b(a.z); o.w = f2b(a.w);
  *(ushort4*)(out + i) = o;
}

// ---------------------------------------------------------------------------
// 128x64-tile bf16 MFMA GEMM (+bias), bf16 out. grid (M/128, N/64).
// Kept only for the tiny Wot GEMM (768x768, K=384).
// ---------------------------------------------------------------------------
template <int BIAS>
__global__ __launch_bounds__(256) void gemm_n64_kernel(
    const ushort* __restrict__ A, const ushort* __restrict__ Bt,
    const float* __restrict__ bias, ushort* __restrict__ C,
    int M, int N, int K) {
  __shared__ __align__(16) ushort Als[128 * 32];
  __shared__ __align__(16) ushort Bls[64 * 32];
  const int tid  = threadIdx.x;
  const int lane = tid & 63;
  const int quad = lane >> 4, l16 = lane & 15;
  const int wu   = __builtin_amdgcn_readfirstlane(tid >> 6);
  const int row0 = blockIdx.x * 128, col0 = blockIdx.y * 64;

  floatx4 acc[2][4] = {};

  for (int k0 = 0; k0 < K; k0 += 32) {
    __syncthreads();
#pragma unroll
    for (int is = 0; is < 2; is++) {
      int c = is * 256 + wu * 64 + lane;
      int m = c >> 2, kk = (c & 3) << 3;
      const ushort* ga = A + (size_t)(row0 + m) * K + (k0 + kk);
      ushort* la = Als + (size_t)(is * 256 + wu * 64) * 8;
      __builtin_amdgcn_global_load_lds(
          (const __attribute__((address_space(1))) void*)ga,
          (__attribute__((address_space(3))) void*)la, 16, 0, 0);
    }
    {
      int c = wu * 64 + lane;
      int m = c >> 2, kk = (c & 3) << 3;
      const ushort* gb = Bt + (size_t)(col0 + m) * K + (k0 + kk);
      ushort* lb = Bls + (size_t)(wu * 64) * 8;
      __builtin_amdgcn_global_load_lds(
          (const __attribute__((address_space(1))) void*)gb,
          (__attribute__((address_space(3))) void*)lb, 16, 0, 0);
    }
    __syncthreads();

    short8 af[2], bf[4];
#pragma unroll
    for (int mt = 0; mt < 2; mt++)
      af[mt] = *(const short8*)(Als + ((wu * 32 + mt * 16 + l16) * 32 + quad * 8));
#pragma unroll
    for (int nt = 0; nt < 4; nt++)
      bf[nt] = *(const short8*)(Bls + ((nt * 16 + l16) * 32 + quad * 8));
#pragma unroll
    for (int mt = 0; mt < 2; mt++)
#pragma unroll
      for (int nt = 0; nt < 4; nt++)
        acc[mt][nt] = __builtin_amdgcn_mfma_f32_16x16x32_bf16(
            af[mt], bf[nt], acc[mt][nt], 0, 0, 0);
  }

#pragma unroll
  for (int mt = 0; mt < 2; mt++) {
#pragma unroll
    for (int nt = 0; nt < 4; nt++) {
      int colg = col0 + nt * 16 + l16;
      float bv_ = BIAS ? bias[colg] : 0.f;
      int rowg0 = row0 + wu * 32 + mt * 16 + quad * 4;
#pragma unroll
      for (int r = 0; r < 4; r++)
        C[(size_t)(rowg0 + r) * N + colg] = f2b(acc[mt][nt][r] + bv_);
    }
  }
}

// ---------------------------------------------------------------------------
// MFMA flash attention v11 (R5-verified). UNCHANGED.
// ---------------------------------------------------------------------------
__global__ __launch_bounds__(256, 3) void attn_mfma_kernel(
    const ushort* __restrict__ Q, const ushort* __restrict__ K,
    const ushort* __restrict__ Vt, const float* __restrict__ mask,
    ushort* __restrict__ O) {
  // bijective decode: bid = (slot*8 + qt)*8 + xcd ; grp = slot*8 + xcd
  const int bid  = blockIdx.x;          // 768 blocks
  const int xcd  = bid & 7;
  const int rest = bid >> 3;            // 0..95
  const int qt   = rest & 7;
  const int grp  = (rest >> 3) * 8 + xcd;   // 0..95, grp%8 == xcd
  const int h = grp % 12, b = grp / 12;

  const int tid = threadIdx.x;
  const int lane = tid & 63;
  const int quad = lane >> 4, l16 = lane & 15;
  const int wu = __builtin_amdgcn_readfirstlane(tid >> 6);
  const int qrow0 = qt * 128 + wu * 32;

  __shared__ __align__(16) ushort Ks[2][64 * 64];   // [buf][key][dh], swz slots
  __shared__ __align__(16) ushort Vts[2][64 * 64];  // [buf][dh][key], swz slots
  __shared__ __align__(16) float Msk[SEQ];          // whole mask row

  // one-time mask row preload (1024 floats, one float4/thread)
  *(float4*)(Msk + tid * 4) = *(const float4*)(mask + (size_t)b * SEQ + tid * 4);

  short8 qf[2][2];
#pragma unroll
  for (int rt = 0; rt < 2; rt++) {
    const ushort* qp = Q + ((size_t)(b * SEQ + qrow0 + rt * 16 + l16)) * D_MODEL
                     + h * DHEAD + quad * 8;
    qf[rt][0] = *(const short8*)qp;
    qf[rt][1] = *(const short8*)(qp + 32);
  }

  // staging decomposition: 64 rows x 8 slots, 2 rounds of 32 rows
  const int j0 = tid >> 3, ck = tid & 7;
  const ushort* Kg = K + ((size_t)(b * SEQ + j0)) * D_MODEL + h * DHEAD + ck * 8;
  const ushort* Vg = Vt + ((size_t)(h * DHEAD + j0)) * BM + b * SEQ + ck * 8;
  const int kloff = j0 * 64 + ((ck ^ (j0 & 7)) << 3);   // (row&7) const over p

  // prologue: chunk 0 -> regs -> buf0; then issue chunk-1 loads
  short8 kst[2], vst[2];
#pragma unroll
  for (int p = 0; p < 2; p++) {
    kst[p] = *(const short8*)(Kg + (size_t)(p * 32) * D_MODEL);
    vst[p] = *(const short8*)(Vg + (size_t)p * (32 * BM));
  }
#pragma unroll
  for (int p = 0; p < 2; p++) {
    *(short8*)(&Ks[0][0] + kloff + p * (32 * 64)) = kst[p];
    *(short8*)(&Vts[0][0] + kloff + p * (32 * 64)) = vst[p];
  }
#pragma unroll
  for (int p = 0; p < 2; p++) {
    kst[p] = *(const short8*)(Kg + (size_t)(64 + p * 32) * D_MODEL);
    vst[p] = *(const short8*)(Vg + 64 + (size_t)p * (32 * BM));
  }
  asm volatile("s_waitcnt lgkmcnt(0)" ::: "memory");
  __builtin_amdgcn_s_barrier();
  asm volatile("" ::: "memory");

  float lsum[2] = {0.f, 0.f};
  floatx4 o_acc[2][4] = {};

  for (int n0 = 0; n0 < SEQ; n0 += 64) {
    const int cur = (n0 >> 6) & 1;

    // (1) write staged regs (chunk i+1) -> buf[cur^1]
    if (n0 + 64 < SEQ) {
#pragma unroll
      for (int p = 0; p < 2; p++) {
        *(short8*)(&Ks[cur ^ 1][0] + kloff + p * (32 * 64)) = kst[p];
        *(short8*)(&Vts[cur ^ 1][0] + kloff + p * (32 * 64)) = vst[p];
      }
      // (2) issue chunk i+2 global loads (land during compute below)
      if (n0 + 128 < SEQ) {
#pragma unroll
        for (int p = 0; p < 2; p++) {
          kst[p] = *(const short8*)(Kg + (size_t)(n0 + 128 + p * 32) * D_MODEL);
          vst[p] = *(const short8*)(Vg + (n0 + 128) + (size_t)p * (32 * BM));
        }
      }
    }

    // (3) compute chunk i from buf[cur]
    __builtin_amdgcn_s_setprio(1);
    unsigned UA[2][4], UB[2][4];
#pragma unroll
    for (int ct = 0; ct < 4; ct++) {
      int krow = ct * 16 + l16;
      int sa = (quad ^ (l16 & 7)) << 3;                 // swizzled 16B slot
      const ushort* kbp = &Ks[cur][0] + krow * 64;
      short8 ka = *(const short8*)(kbp + sa);           // K[krow][quad*8..]
      short8 kb = *(const short8*)(kbp + (sa ^ 32));    // K[krow][32+quad*8..]
      float4 mk = *(const float4*)(Msk + n0 + ct * 16 + quad * 4);
#pragma unroll
      for (int rt = 0; rt < 2; rt++) {
        floatx4 st = {};
        st = __builtin_amdgcn_mfma_f32_16x16x32_bf16(ka, qf[rt][0], st, 0, 0, 0);
        st = __builtin_amdgcn_mfma_f32_16x16x32_bf16(kb, qf[rt][1], st, 0, 0, 0);
        float e0 = __expf(st[0] + mk.x);     // Q pre-scaled by 1/sqrt(dh)
        float e1 = __expf(st[1] + mk.y);
        float e2 = __expf(st[2] + mk.z);
        float e3 = __expf(st[3] + mk.w);
        lsum[rt] += (e0 + e1) + (e2 + e3);
        UA[rt][ct] = pk2(e0, e1);            // keys quad*4+0,1 (query l16)
        UB[rt][ct] = pk2(e2, e3);            // keys quad*4+2,3
      }
    }

#pragma unroll
    for (int kk = 0; kk < 2; kk++) {
      short8 pa[2];
#pragma unroll
      for (int rt = 0; rt < 2; rt++) {
        // in-register P transpose: dest quad q, dword w <- keys q*8+2w,+2w+1
        unsigned a0 = UA[rt][2 * kk], a2 = UA[rt][2 * kk + 1];
        unsigned b1 = UB[rt][2 * kk], b3 = UB[rt][2 * kk + 1];
        asm("v_permlane32_swap_b32 %0, %1" : "+v"(a0), "+v"(a2));
        asm("v_permlane16_swap_b32 %0, %1" : "+v"(a0), "+v"(a2));
        asm("v_permlane32_swap_b32 %0, %1" : "+v"(b1), "+v"(b3));
        asm("v_permlane16_swap_b32 %0, %1" : "+v"(b1), "+v"(b3));
        int4 t;
        t.x = (int)a0;   // keys q*8+0,1
        t.y = (int)b1;   // keys q*8+2,3
        t.z = (int)a2;   // keys q*8+4,5
        t.w = (int)b3;   // keys q*8+6,7
        pa[rt] = *(short8*)&t;
      }
#pragma unroll
      for (int dt = 0; dt < 4; dt++) {
        int vr = dt * 16 + l16;
        short8 vb = *(const short8*)(&Vts[cur][0] + vr * 64
                                     + (((kk * 4 + quad) ^ (l16 & 7)) << 3));
#pragma unroll
        for (int rt = 0; rt < 2; rt++)
          o_acc[rt][dt] = __builtin_amdgcn_mfma_f32_16x16x32_bf16(
              pa[rt], vb, o_acc[rt][dt], 0, 0, 0);
      }
    }
    __builtin_amdgcn_s_setprio(0);

    // (4) one barrier per chunk (drain own ds_writes first)
    if (n0 + 64 < SEQ) {
      asm volatile("s_waitcnt lgkmcnt(0)" ::: "memory");
      __builtin_amdgcn_s_barrier();
      asm volatile("" ::: "memory");
    }
  }

#pragma unroll
  for (int rt = 0; rt < 2; rt++) {
    float l = lsum[rt];
    l += __shfl_xor(l, 16);
    l += __shfl_xor(l, 32);
    float inv = 1.f / l;
    int lanebase = lane & 48;
#pragma unroll
    for (int rr = 0; rr < 4; rr++) {
      int iv = __builtin_amdgcn_ds_bpermute((lanebase | (quad * 4 + rr)) << 2,
                                            __float_as_int(inv));
      float invr = __int_as_float(iv);
      size_t rowg = (size_t)(b * SEQ + qrow0 + rt * 16 + quad * 4 + rr);
#pragma unroll
      for (int dt = 0; dt < 4; dt++)
        O[rowg * D_MODEL + h * DHEAD + dt * 16 + l16] = f2b(o_acc[rt][dt][rr] * invr);
    }
  }
}

// ---------------------------------------------------------------------------
// out = LayerNorm(Ain + Bin)*g + bt. Bin bf16. Ain fp32 or bf16.
// ---------------------------------------------------------------------------
template <int AIN_BF16, int OUT_FP32, int OUT_BF16>
__global__ __launch_bounds__(256) void add_ln_kernel(
    const float* __restrict__ Ainf, const ushort* __restrict__ Ainb,
    const ushort* __restrict__ Binb,
    const float* __restrict__ g, const float* __restrict__ bt,
    float* __restrict__ outf, ushort* __restrict__ outb) {
  const int row = blockIdx.x, tid = threadIdx.x;
  __shared__ float red[4];
  float v[3];
  float s = 0.f;
#pragma unroll
  for (int u = 0; u < 3; u++) {
    int c = tid + u * 256;
    float a = AIN_BF16 ? b2f(Ainb[(size_t)row * 768 + c]) : Ainf[(size_t)row * 768 + c];
    v[u] = a + b2f(Binb[(size_t)row * 768 + c]);
    s += v[u];
  }
#pragma unroll
  for (int off = 32; off > 0; off >>= 1) s += __shfl_down(s, off);
  if ((tid & 63) == 0) red[tid >> 6] = s;
  __syncthreads();
  float mu = (red[0] + red[1] + red[2] + red[3]) * (1.f / 768.f);
  float s2 = 0.f;
#pragma unroll
  for (int u = 0; u < 3; u++) { float d = v[u] - mu; s2 += d * d; }
#pragma unroll
  for (int off = 32; off > 0; off >>= 1) s2 += __shfl_down(s2, off);
  __syncthreads();
  if ((tid & 63) == 0) red[tid >> 6] = s2;
  __syncthreads();
  float var = (red[0] + red[1] + red[2] + red[3]) * (1.f / 768.f);
  float inv = rsqrtf(var + 1e-12f);
#pragma unroll
  for (int u = 0; u < 3; u++) {
    int c = tid + u * 256;
    float r = g[c] * (v[u] - mu) * inv + bt[c];
    if (OUT_FP32) outf[(size_t)row * 768 + c] = r;
    if (OUT_BF16) outb[(size_t)row * 768 + c] = f2b(r);
  }
}

// ---------------------------------------------------------------------------
extern "C" void kernel_launch(void* const* d_in, const int* in_sizes, int n_in,
                              void* d_out, int out_size, void* d_ws, size_t ws_size,
                              hipStream_t stream) {
  const float* x    = (const float*)d_in[0];
  const float* mask = (const float*)d_in[1];
  const float* Pq   = (const float*)d_in[2];
  const float* Vq   = (const float*)d_in[3];
  const float* bq   = (const float*)d_in[4];
  const float* Pk   = (const float*)d_in[5];
  const float* Vk   = (const float*)d_in[6];
  const float* bk   = (const float*)d_in[7];
  const float* Pv   = (const float*)d_in[8];
  const float* Vv   = (const float*)d_in[9];
  const float* bv   = (const float*)d_in[10];
  const float* Uo   = (const float*)d_in[11];
  const float* Vo   = (const float*)d_in[12];
  const float* bo   = (const float*)d_in[13];
  const float* U1   = (const float*)d_in[14];
  const float* V1   = (const float*)d_in[15];
  const float* b1   = (const float*)d_in[16];
  const float* U2   = (const float*)d_in[17];
  const float* V2   = (const float*)d_in[18];
  const float* b2   = (const float*)d_in[19];
  const float* g1   = (const float*)d_in[20];
  const float* be1  = (const float*)d_in[21];
  const float* g2   = (const float*)d_in[22];
  const float* be2  = (const float*)d_in[23];

  // --- workspace carve (bytes, 256-aligned) ---
  char* w = (char*)d_ws;
  auto alloc = [&](size_t bytes) -> char* {
    char* p = w; w += (bytes + 255) & ~(size_t)255; return p;
  };
  ushort* xb     = (ushort*)alloc((size_t)BM * 768 * 2);
  ushort* Wqkvt  = (ushort*)alloc((size_t)2304 * 768 * 2);
  float*  ball   = (float*)alloc(2304 * 4);
  ushort* VoT    = (ushort*)alloc(768 * 384 * 2);   // Vo^T bf16 (A operand)
  ushort* Uob    = (ushort*)alloc(768 * 384 * 2);   // Uo bf16 (Bt operand)
  ushort* Wot    = (ushort*)alloc(768 * 768 * 2);   // Vo^T @ Uo^T = Wo^T
  ushort* U1t    = (ushort*)alloc(384 * 768 * 2);
  ushort* V1t    = (ushort*)alloc((size_t)3072 * 384 * 2);
  ushort* U2t    = (ushort*)alloc((size_t)384 * 3072 * 2);
  ushort* V2t    = (ushort*)alloc(768 * 384 * 2);
  ushort* Qb     = (ushort*)alloc((size_t)BM * 768 * 2);
  ushort* Kb     = (ushort*)alloc((size_t)BM * 768 * 2);
  ushort* Vtb    = (ushort*)alloc((size_t)768 * BM * 2);
  ushort* attnb  = (ushort*)alloc((size_t)BM * 768 * 2);
  ushort* mtb    = (ushort*)alloc((size_t)BM * 384 * 2);   // mid / t2
  ushort* y1b    = (ushort*)alloc((size_t)BM * 768 * 2);
  ushort* x1b    = (ushort*)alloc((size_t)BM * 768 * 2);
  float*  part   = (float*)alloc((size_t)4 * BM * 384 * 4);
  // aliases (dead-buffer reuse)
  ushort* hiddenb = Qb;             // Qb..attnb (50.3 MB) dead after y1 GEMM
  ushort* y2b     = y1b;            // y1b dead after LN1
  float*  outp    = (float*)d_out;

  // 1) conversions / weight prep
  f2b_kernel<<<(BM * 768) / 1024, 256, 0, stream>>>(x, xb, BM * 768);
  combine_qkv_kernel<<<dim3(2304, 3), 256, 0, stream>>>(Pq, Vq, Pk, Vk, Pv, Vv, Wqkvt);
  concat_bias_kernel<<<9, 256, 0, stream>>>(bq, bk, bv, ball);
  prep_weights_kernel<<<3456, 256, 0, stream>>>(U1, V1, U2, V2, Vo, Uo,
                                                U1t, V1t, U2t, V2t, VoT, Uob);
  // Wot[n][d] = sum_r Vo^T[n][r] * Uo[d][r]  (= Wo[d][n], the Bt operand for y1)
  gemm_n64_kernel<0><<<dim3(6, 12), 256, 0, stream>>>(VoT, Uob, nullptr, Wot, 768, 768, 384);

  // 2) fused QKV = x @ [Wq|Wk|Wv] + bias  (bf16 A staging -- R7-verified)
  gemm_mfma_kernel<3, 1, 0><<<dim3(64, 18), 256, 0, stream>>>(
      xb, Wqkvt, ball, Qb, Kb, Vtb, BM, 2304, 768);

  // 3) MFMA flash attention (dbuf 1-barrier pipeline) -> bf16 (B*M, 768)
  attn_mfma_kernel<<<dim3(768), 256, 0, stream>>>(Qb, Kb, Vtb, mask, attnb);

  // 4) attn out-projection: y1 = attn @ Wo + bo  (128^2 piped GEMM)
  gemm_mfma_kernel<1, 1, 0><<<dim3(64, 6), 256, 0, stream>>>(
      attnb, Wot, bo, y1b, nullptr, nullptr, BM, 768, 768);
  add_ln_kernel<0, 0, 1><<<BM, 256, 0, stream>>>(x, nullptr, y1b, g1, be1, nullptr, x1b);

  // 5) FFN (low rank) with fast GELU
  gemm_mfma_kernel<1, 0, 0><<<dim3(64, 3), 256, 0, stream>>>(
      x1b, U1t, nullptr, mtb, nullptr, nullptr, BM, 384, 768);
  gemm_mfma_kernel<1, 1, 1><<<dim3(64, 24), 256, 0, stream>>>(
      mtb, V1t, b1, hiddenb, nullptr, nullptr, BM, 3072, 384);
  //    t2 = hidden @ U2 (K=3072): piped splitk S=2
  gemm_piped_splitk_kernel<<<dim3(64, 3, 2), 256, 0, stream>>>(
      hiddenb, U2t, part, BM, 384, 3072, 1536);
  reduce_splitk_kernel<<<(BM * 384) / 1024, 256, 0, stream>>>(part, mtb, BM * 384, 2);
  gemm_mfma_kernel<1, 1, 0><<<dim3(64, 6), 256, 0, stream>>>(
      mtb, V2t, b2, y2b, nullptr, nullptr, BM, 768, 384);

  // 6) residual + LN2 -> output (fp32)
  add_ln_kernel<1, 1, 0><<<BM, 256, 0, stream>>>(nullptr, x1b, y2b, g2, be2, outp, nullptr);
}

// Round 11
// 380.911 us; speedup vs baseline: 1.1129x; 1.0194x over previous
//
#include <hip/hip_runtime.h>
#include <cstddef>

// Problem constants
#define D_MODEL 768
#define NHEAD   12
#define DHEAD   64
#define RANK    32
#define SEQ     1024
#define BATCH   8
#define BM      8192      // BATCH*SEQ

typedef __attribute__((ext_vector_type(8))) short short8;
typedef __attribute__((ext_vector_type(4))) float floatx4;

__device__ inline ushort f2b(float f) {           // fp32 -> bf16 RNE
  union { float f; unsigned u; } v; v.f = f;
  unsigned r = v.u + 0x7fffu + ((v.u >> 16) & 1u);
  return (ushort)(r >> 16);
}
__device__ inline float b2f(ushort h) {
  union { unsigned u; float f; } v; v.u = ((unsigned)h) << 16;
  return v.f;
}
// pack two fp32 -> bf16x2 dword
__device__ inline unsigned pk2(float a, float b) {
  return ((__float_as_uint(b) + 0x8000u) & 0xffff0000u) |
         ((__float_as_uint(a) + 0x8000u) >> 16);
}
// tanh-form GELU with fast exp (max |err vs erf-GELU| ~1e-3)
__device__ inline float fast_gelu(float x) {
  float z = 0.79788456080286536f * (x + 0.044715f * x * x * x);
  float e = __expf(2.f * z);
  float t = 1.f - 2.f / (e + 1.f);
  return 0.5f * x * (1.f + t);
}

// ---------------------------------------------------------------------------
__global__ __launch_bounds__(256) void f2b_kernel(
    const float* __restrict__ in, ushort* __restrict__ out, int n) {
  int i = (blockIdx.x * 256 + threadIdx.x) * 4;
  if (i >= n) return;
  float4 v = *(const float4*)(in + i);
  ushort4 o;
  o.x = f2b(v.x); o.y = f2b(v.y); o.z = f2b(v.z); o.w = f2b(v.w);
  *(ushort4*)(out + i) = o;
}

// ---------------------------------------------------------------------------
// All three QKV low-rank combines in one launch (grid.y selects q/k/v):
// Wt[y][c=h*64+k][d] = sum_r P[h,d,r] * Vw[h,r,k]
// ---------------------------------------------------------------------------
__global__ __launch_bounds__(256) void combine_qkv_kernel(
    const float* __restrict__ Pq, const float* __restrict__ Vq,
    const float* __restrict__ Pk, const float* __restrict__ Vk,
    const float* __restrict__ Pv, const float* __restrict__ Vv,
    ushort* __restrict__ Wt) {
  int which = blockIdx.y;
  const float* P  = which == 0 ? Pq : (which == 1 ? Pk : Pv);
  const float* Vw = which == 0 ? Vq : (which == 1 ? Vk : Vv);
  ushort* W = Wt + (size_t)which * D_MODEL * D_MODEL;
  int idx = blockIdx.x * 256 + threadIdx.x;
  if (idx >= D_MODEL * NHEAD * DHEAD) return;
  int c = idx / D_MODEL;
  int d = idx - c * D_MODEL;
  int h = c >> 6, k = c & 63;
  const float* p = P + ((size_t)h * D_MODEL + d) * RANK;
  const float* v = Vw + (size_t)h * RANK * DHEAD + k;
  float s = 0.f;
#pragma unroll
  for (int r = 0; r < RANK; r++) s += p[r] * v[(size_t)r * DHEAD];
  W[(size_t)c * D_MODEL + d] = f2b(s);
}

__global__ __launch_bounds__(256) void concat_bias_kernel(
    const float* __restrict__ bq, const float* __restrict__ bk,
    const float* __restrict__ bv, float* __restrict__ out) {
  int i = blockIdx.x * 256 + threadIdx.x;
  if (i >= 2304) return;
  out[i] = (i < 768) ? bq[i] : (i < 1536 ? bk[i - 768] : bv[i - 1536]);
}

// ---------------------------------------------------------------------------
// Six weight preps in one launch (block-range decode):
// transposes (fp32 (R,C) -> bf16 (C,R)): U1(768,384) V1(384,3072)
//   U2(3072,384) V2(384,768) Vo(384,768)
// plus straight f2b copy of Uo (768x384) for the Wot GEMM's Bt operand.
// ---------------------------------------------------------------------------
__global__ __launch_bounds__(256) void prep_weights_kernel(
    const float* __restrict__ U1, const float* __restrict__ V1,
    const float* __restrict__ U2, const float* __restrict__ V2,
    const float* __restrict__ Vo, const float* __restrict__ Uo,
    ushort* __restrict__ U1t, ushort* __restrict__ V1t,
    ushort* __restrict__ U2t, ushort* __restrict__ V2t,
    ushort* __restrict__ VoT, ushort* __restrict__ Uob) {
  __shared__ float t[32][33];
  int blk = blockIdx.x;
  if (blk >= 3168) {                 // Uo f2b copy: 288 blocks x 1024 elems
    int i = (blk - 3168) * 1024 + threadIdx.x * 4;
    float4 v = *(const float4*)(Uo + i);
    ushort4 o;
    o.x = f2b(v.x); o.y = f2b(v.y); o.z = f2b(v.z); o.w = f2b(v.w);
    *(ushort4*)(Uob + i) = o;
    return;
  }
  const float* in; ushort* out; int R, C, bx, by;
  if (blk < 288)       { in = U1; out = U1t; R = 768;  C = 384;  int i = blk;        bx = i % 12; by = i / 12; }
  else if (blk < 1440) { in = V1; out = V1t; R = 384;  C = 3072; int i = blk - 288;  bx = i % 96; by = i / 96; }
  else if (blk < 2592) { in = U2; out = U2t; R = 3072; C = 384;  int i = blk - 1440; bx = i % 12; by = i / 12; }
  else if (blk < 2880) { in = V2; out = V2t; R = 384;  C = 768;  int i = blk - 2592; bx = i % 24; by = i / 24; }
  else                 { in = Vo; out = VoT; R = 384;  C = 768;  int i = blk - 2880; bx = i % 24; by = i / 24; }
  int c0 = bx * 32, r0 = by * 32;
  int lx = threadIdx.x & 31, ly = threadIdx.x >> 5;
#pragma unroll
  for (int i = 0; i < 32; i += 8)
    t[ly + i][lx] = in[(size_t)(r0 + ly + i) * C + c0 + lx];
  __syncthreads();
#pragma unroll
  for (int i = 0; i < 32; i += 8)
    out[(size_t)(c0 + ly + i) * R + r0 + lx] = f2b(t[lx][ly + i]);
}

// ---------------------------------------------------------------------------
// bf16 MFMA GEMM v2 (R7-verified structure): 128^2, BK=64, reg-staged dbuf,
// ONE raw barrier per K-step, lgkmcnt-only drain (VMEM for step s+2 stays in
// flight across the barrier), XOR-swizzled 16B slots both sides, setprio
// around the MFMA cluster.
// OUTMODE: 1 bf16 (M,N); 3 fused QKV (Q pre-scaled 1/8; V transposed out).
// grid (M/128, N/128): x = M-block (R6 XCD A-reuse).
// ---------------------------------------------------------------------------
template <int OUTMODE, int BIAS, int GELU>
__global__ __launch_bounds__(256, 2) void gemm_mfma_kernel(
    const ushort* __restrict__ A, const ushort* __restrict__ Bt,
    const float* __restrict__ bias, void* __restrict__ C,
    void* __restrict__ C2, void* __restrict__ C3,
    int M, int N, int K) {
  __shared__ __align__(16) ushort Als[2][128 * 64];
  __shared__ __align__(16) ushort Bls[2][128 * 64];
  const int tid  = threadIdx.x;
  const int lane = tid & 63;
  const int quad = lane >> 4, l16 = lane & 15;
  const int wu   = __builtin_amdgcn_readfirstlane(tid >> 6);
  const int wrow = (wu >> 1) * 64, wcol = (wu & 1) * 64;
  const int row0 = blockIdx.x * 128, col0 = blockIdx.y * 128;

  const int r_ = tid >> 3, sl_ = tid & 7;
  const ushort* Ag = A + (size_t)(row0 + r_) * K + sl_ * 8;
  const ushort* Bg = Bt + (size_t)(col0 + r_) * K + sl_ * 8;
  const int loff = r_ * 64 + ((sl_ ^ (r_ & 7)) << 3);

  const int nsteps = K >> 6;
  short8 ast[4], bst[4];

  // prologue: step-0 tile -> regs -> buf0; then issue step-1 loads
#pragma unroll
  for (int p = 0; p < 4; p++) {
    ast[p] = *(const short8*)(Ag + (size_t)(32 * p) * K);
    bst[p] = *(const short8*)(Bg + (size_t)(32 * p) * K);
  }
#pragma unroll
  for (int p = 0; p < 4; p++) {
    *(short8*)(&Als[0][0] + loff + p * (32 * 64)) = ast[p];
    *(short8*)(&Bls[0][0] + loff + p * (32 * 64)) = bst[p];
  }
#pragma unroll
  for (int p = 0; p < 4; p++) {
    ast[p] = *(const short8*)(Ag + (size_t)(32 * p) * K + 64);
    bst[p] = *(const short8*)(Bg + (size_t)(32 * p) * K + 64);
  }
  asm volatile("s_waitcnt lgkmcnt(0)" ::: "memory");
  __builtin_amdgcn_s_barrier();
  asm volatile("" ::: "memory");

  floatx4 acc[4][4] = {};

  for (int s = 0; s < nsteps; s++) {
    const int cur = s & 1;

    if (s + 1 < nsteps) {
#pragma unroll
      for (int p = 0; p < 4; p++) {
        *(short8*)(&Als[cur ^ 1][0] + loff + p * (32 * 64)) = ast[p];
        *(short8*)(&Bls[cur ^ 1][0] + loff + p * (32 * 64)) = bst[p];
      }
      if (s + 2 < nsteps) {
        const int ko = (s + 2) * 64;
#pragma unroll
        for (int p = 0; p < 4; p++) {
          ast[p] = *(const short8*)(Ag + (size_t)(32 * p) * K + ko);
          bst[p] = *(const short8*)(Bg + (size_t)(32 * p) * K + ko);
        }
      }
    }

    __builtin_amdgcn_s_setprio(1);
#pragma unroll
    for (int kk = 0; kk < 2; kk++) {
      short8 af[4], bf[4];
#pragma unroll
      for (int mt = 0; mt < 4; mt++) {
        int row = wrow + mt * 16 + l16;
        af[mt] = *(const short8*)(&Als[cur][0] + row * 64
                                  + (((kk * 4 + quad) ^ (l16 & 7)) << 3));
      }
#pragma unroll
      for (int nt = 0; nt < 4; nt++) {
        int row = wcol + nt * 16 + l16;
        bf[nt] = *(const short8*)(&Bls[cur][0] + row * 64
                                  + (((kk * 4 + quad) ^ (l16 & 7)) << 3));
      }
#pragma unroll
      for (int mt = 0; mt < 4; mt++)
#pragma unroll
        for (int nt = 0; nt < 4; nt++)
          acc[mt][nt] = __builtin_amdgcn_mfma_f32_16x16x32_bf16(
              af[mt], bf[nt], acc[mt][nt], 0, 0, 0);
    }
    __builtin_amdgcn_s_setprio(0);

    if (s + 1 < nsteps) {
      asm volatile("s_waitcnt lgkmcnt(0)" ::: "memory");
      __builtin_amdgcn_s_barrier();
      asm volatile("" ::: "memory");
    }
  }

#pragma unroll
  for (int mt = 0; mt < 4; mt++) {
#pragma unroll
    for (int nt = 0; nt < 4; nt++) {
      int colg = col0 + wcol + nt * 16 + l16;
      float bv_ = BIAS ? bias[colg] : 0.f;
      float v4[4];
#pragma unroll
      for (int r = 0; r < 4; r++) {
        float v = acc[mt][nt][r] + bv_;
        if (GELU) v = fast_gelu(v);
        v4[r] = v;
      }
      int rowg0 = row0 + wrow + mt * 16 + quad * 4;
      if (OUTMODE == 3) {
        int seg = col0 / 768;
        int cl = colg - seg * 768;
        if (seg == 2) {
          ushort4 o;
          o.x = f2b(v4[0]); o.y = f2b(v4[1]); o.z = f2b(v4[2]); o.w = f2b(v4[3]);
          *(ushort4*)((ushort*)C3 + (size_t)cl * BM + rowg0) = o;
        } else {
          ushort* dst = (seg == 0) ? (ushort*)C : (ushort*)C2;
          float sc = (seg == 0) ? 0.125f : 1.f;   // fold 1/sqrt(64) into Q
#pragma unroll
          for (int r = 0; r < 4; r++)
            dst[(size_t)(rowg0 + r) * D_MODEL + cl] = f2b(v4[r] * sc);
        }
      } else {
#pragma unroll
        for (int r = 0; r < 4; r++)
          ((ushort*)C)[(size_t)(rowg0 + r) * N + colg] = f2b(v4[r]);
      }
    }
  }
}

// ---------------------------------------------------------------------------
// Piped 128x64-tile bf16 MFMA GEMM (R11): same R7 pipeline (reg-staged dbuf,
// one raw barrier/step, lgkmcnt-only drain, swizzled slots, setprio), but
// half-width B tile -> LDS 48 KB -> 3 blocks/CU. For small-N GEMMs (y1,
// FFN1, V2) whose 128^2 grids (192-384 blocks) starved CUs at 2 blocks/CU.
// 4 waves, each owns a 32x64 output (acc[2][4]). grid (M/128, N/64).
// ---------------------------------------------------------------------------
template <int BIAS, int GELU>
__global__ __launch_bounds__(256, 3) void gemm_piped_n64_kernel(
    const ushort* __restrict__ A, const ushort* __restrict__ Bt,
    const float* __restrict__ bias, ushort* __restrict__ C,
    int M, int N, int K) {
  __shared__ __align__(16) ushort Als[2][128 * 64];
  __shared__ __align__(16) ushort Bls[2][64 * 64];
  const int tid  = threadIdx.x;
  const int lane = tid & 63;
  const int quad = lane >> 4, l16 = lane & 15;
  const int wu   = __builtin_amdgcn_readfirstlane(tid >> 6);
  const int row0 = blockIdx.x * 128, col0 = blockIdx.y * 64;

  const int r_ = tid >> 3, sl_ = tid & 7;      // r_ 0..31, slot 0..7
  const ushort* Ag = A + (size_t)(row0 + r_) * K + sl_ * 8;
  const ushort* Bg = Bt + (size_t)(col0 + r_) * K + sl_ * 8;
  const int loff = r_ * 64 + ((sl_ ^ (r_ & 7)) << 3);  // (r&7) const over p

  const int nsteps = K >> 6;
  short8 ast[4], bst[2];

  // prologue: step-0 tile -> regs -> buf0; then issue step-1 loads
#pragma unroll
  for (int p = 0; p < 4; p++)
    ast[p] = *(const short8*)(Ag + (size_t)(32 * p) * K);
#pragma unroll
  for (int p = 0; p < 2; p++)
    bst[p] = *(const short8*)(Bg + (size_t)(32 * p) * K);
#pragma unroll
  for (int p = 0; p < 4; p++)
    *(short8*)(&Als[0][0] + loff + p * (32 * 64)) = ast[p];
#pragma unroll
  for (int p = 0; p < 2; p++)
    *(short8*)(&Bls[0][0] + loff + p * (32 * 64)) = bst[p];
#pragma unroll
  for (int p = 0; p < 4; p++)
    ast[p] = *(const short8*)(Ag + (size_t)(32 * p) * K + 64);
#pragma unroll
  for (int p = 0; p < 2; p++)
    bst[p] = *(const short8*)(Bg + (size_t)(32 * p) * K + 64);
  asm volatile("s_waitcnt lgkmcnt(0)" ::: "memory");
  __builtin_amdgcn_s_barrier();
  asm volatile("" ::: "memory");

  floatx4 acc[2][4] = {};

  for (int s = 0; s < nsteps; s++) {
    const int cur = s & 1;

    if (s + 1 < nsteps) {
#pragma unroll
      for (int p = 0; p < 4; p++)
        *(short8*)(&Als[cur ^ 1][0] + loff + p * (32 * 64)) = ast[p];
#pragma unroll
      for (int p = 0; p < 2; p++)
        *(short8*)(&Bls[cur ^ 1][0] + loff + p * (32 * 64)) = bst[p];
      if (s + 2 < nsteps) {
        const int ko = (s + 2) * 64;
#pragma unroll
        for (int p = 0; p < 4; p++)
          ast[p] = *(const short8*)(Ag + (size_t)(32 * p) * K + ko);
#pragma unroll
        for (int p = 0; p < 2; p++)
          bst[p] = *(const short8*)(Bg + (size_t)(32 * p) * K + ko);
      }
    }

    __builtin_amdgcn_s_setprio(1);
#pragma unroll
    for (int kk = 0; kk < 2; kk++) {
      short8 af[2], bf[4];
#pragma unroll
      for (int mt = 0; mt < 2; mt++) {
        int row = wu * 32 + mt * 16 + l16;
        af[mt] = *(const short8*)(&Als[cur][0] + row * 64
                                  + (((kk * 4 + quad) ^ (l16 & 7)) << 3));
      }
#pragma unroll
      for (int nt = 0; nt < 4; nt++) {
        int row = nt * 16 + l16;
        bf[nt] = *(const short8*)(&Bls[cur][0] + row * 64
                                  + (((kk * 4 + quad) ^ (l16 & 7)) << 3));
      }
#pragma unroll
      for (int mt = 0; mt < 2; mt++)
#pragma unroll
        for (int nt = 0; nt < 4; nt++)
          acc[mt][nt] = __builtin_amdgcn_mfma_f32_16x16x32_bf16(
              af[mt], bf[nt], acc[mt][nt], 0, 0, 0);
    }
    __builtin_amdgcn_s_setprio(0);

    if (s + 1 < nsteps) {
      asm volatile("s_waitcnt lgkmcnt(0)" ::: "memory");
      __builtin_amdgcn_s_barrier();
      asm volatile("" ::: "memory");
    }
  }

#pragma unroll
  for (int mt = 0; mt < 2; mt++) {
#pragma unroll
    for (int nt = 0; nt < 4; nt++) {
      int colg = col0 + nt * 16 + l16;
      float bv_ = BIAS ? bias[colg] : 0.f;
      int rowg0 = row0 + wu * 32 + mt * 16 + quad * 4;
#pragma unroll
      for (int r = 0; r < 4; r++) {
        float v = acc[mt][nt][r] + bv_;
        if (GELU) v = fast_gelu(v);
        C[(size_t)(rowg0 + r) * N + colg] = f2b(v);
      }
    }
  }
}

// ---------------------------------------------------------------------------
// Piped split-K bf16 MFMA GEMM (R9-verified): same R7 pipeline, K-range
// [kbase, kbase+Kper), fp32 partial output. grid (M/128, N/128, S).
// ---------------------------------------------------------------------------
__global__ __launch_bounds__(256, 2) void gemm_piped_splitk_kernel(
    const ushort* __restrict__ A, const ushort* __restrict__ Bt,
    float* __restrict__ Cpart, int M, int N, int Ktot, int Kper) {
  __shared__ __align__(16) ushort Als[2][128 * 64];
  __shared__ __align__(16) ushort Bls[2][128 * 64];
  const int tid  = threadIdx.x;
  const int lane = tid & 63;
  const int quad = lane >> 4, l16 = lane & 15;
  const int wu   = __builtin_amdgcn_readfirstlane(tid >> 6);
  const int wrow = (wu >> 1) * 64, wcol = (wu & 1) * 64;
  const int row0 = blockIdx.x * 128, col0 = blockIdx.y * 128;
  const int kbase = blockIdx.z * Kper;
  float* Cz = Cpart + (size_t)blockIdx.z * M * N;

  const int r_ = tid >> 3, sl_ = tid & 7;
  const ushort* Ag = A + (size_t)(row0 + r_) * Ktot + kbase + sl_ * 8;
  const ushort* Bg = Bt + (size_t)(col0 + r_) * Ktot + kbase + sl_ * 8;
  const int loff = r_ * 64 + ((sl_ ^ (r_ & 7)) << 3);

  const int nsteps = Kper >> 6;
  short8 ast[4], bst[4];

#pragma unroll
  for (int p = 0; p < 4; p++) {
    ast[p] = *(const short8*)(Ag + (size_t)(32 * p) * Ktot);
    bst[p] = *(const short8*)(Bg + (size_t)(32 * p) * Ktot);
  }
#pragma unroll
  for (int p = 0; p < 4; p++) {
    *(short8*)(&Als[0][0] + loff + p * (32 * 64)) = ast[p];
    *(short8*)(&Bls[0][0] + loff + p * (32 * 64)) = bst[p];
  }
#pragma unroll
  for (int p = 0; p < 4; p++) {
    ast[p] = *(const short8*)(Ag + (size_t)(32 * p) * Ktot + 64);
    bst[p] = *(const short8*)(Bg + (size_t)(32 * p) * Ktot + 64);
  }
  asm volatile("s_waitcnt lgkmcnt(0)" ::: "memory");
  __builtin_amdgcn_s_barrier();
  asm volatile("" ::: "memory");

  floatx4 acc[4][4] = {};

  for (int s = 0; s < nsteps; s++) {
    const int cur = s & 1;

    if (s + 1 < nsteps) {
#pragma unroll
      for (int p = 0; p < 4; p++) {
        *(short8*)(&Als[cur ^ 1][0] + loff + p * (32 * 64)) = ast[p];
        *(short8*)(&Bls[cur ^ 1][0] + loff + p * (32 * 64)) = bst[p];
      }
      if (s + 2 < nsteps) {
        const int ko = (s + 2) * 64;
#pragma unroll
        for (int p = 0; p < 4; p++) {
          ast[p] = *(const short8*)(Ag + (size_t)(32 * p) * Ktot + ko);
          bst[p] = *(const short8*)(Bg + (size_t)(32 * p) * Ktot + ko);
        }
      }
    }

    __builtin_amdgcn_s_setprio(1);
#pragma unroll
    for (int kk = 0; kk < 2; kk++) {
      short8 af[4], bf[4];
#pragma unroll
      for (int mt = 0; mt < 4; mt++) {
        int row = wrow + mt * 16 + l16;
        af[mt] = *(const short8*)(&Als[cur][0] + row * 64
                                  + (((kk * 4 + quad) ^ (l16 & 7)) << 3));
      }
#pragma unroll
      for (int nt = 0; nt < 4; nt++) {
        int row = wcol + nt * 16 + l16;
        bf[nt] = *(const short8*)(&Bls[cur][0] + row * 64
                                  + (((kk * 4 + quad) ^ (l16 & 7)) << 3));
      }
#pragma unroll
      for (int mt = 0; mt < 4; mt++)
#pragma unroll
        for (int nt = 0; nt < 4; nt++)
          acc[mt][nt] = __builtin_amdgcn_mfma_f32_16x16x32_bf16(
              af[mt], bf[nt], acc[mt][nt], 0, 0, 0);
    }
    __builtin_amdgcn_s_setprio(0);

    if (s + 1 < nsteps) {
      asm volatile("s_waitcnt lgkmcnt(0)" ::: "memory");
      __builtin_amdgcn_s_barrier();
      asm volatile("" ::: "memory");
    }
  }

#pragma unroll
  for (int mt = 0; mt < 4; mt++)
#pragma unroll
    for (int nt = 0; nt < 4; nt++) {
      int colg = col0 + wcol + nt * 16 + l16;
      int rowg0 = row0 + wrow + mt * 16 + quad * 4;
#pragma unroll
      for (int r = 0; r < 4; r++)
        Cz[(size_t)(rowg0 + r) * N + colg] = acc[mt][nt][r];
    }
}

__global__ __launch_bounds__(256) void reduce_splitk_kernel(
    const float* __restrict__ part, ushort* __restrict__ out, int n, int S) {
  int i = (blockIdx.x * 256 + threadIdx.x) * 4;
  if (i >= n) return;
  float4 a = *(const float4*)(part + i);
  for (int s = 1; s < S; s++) {
    float4 b = *(const float4*)(part + (size_t)s * n + i);
    a.x += b.x; a.y += b.y; a.z += b.z; a.w += b.w;
  }
  ushort4 o;
  o.x = f2b(a.x); o.y = f2b(a.y); o.z = f2b(a.z); o.w = f2b(a.w);
  *(ushort4*)(out + i) = o;
}

// ---------------------------------------------------------------------------
// 128x64-tile bf16 MFMA GEMM (+bias), bf16 out. grid (M/128, N/64).
// Kept only for the tiny Wot GEMM (768x768, K=384).
// ---------------------------------------------------------------------------
template <int BIAS>
__global__ __launch_bounds__(256) void gemm_n64_kernel(
    const ushort* __restrict__ A, const ushort* __restrict__ Bt,
    const float* __restrict__ bias, ushort* __restrict__ C,
    int M, int N, int K) {
  __shared__ __align__(16) ushort Als[128 * 32];
  __shared__ __align__(16) ushort Bls[64 * 32];
  const int tid  = threadIdx.x;
  const int lane = tid & 63;
  const int quad = lane >> 4, l16 = lane & 15;
  const int wu   = __builtin_amdgcn_readfirstlane(tid >> 6);
  const int row0 = blockIdx.x * 128, col0 = blockIdx.y * 64;

  floatx4 acc[2][4] = {};

  for (int k0 = 0; k0 < K; k0 += 32) {
    __syncthreads();
#pragma unroll
    for (int is = 0; is < 2; is++) {
      int c = is * 256 + wu * 64 + lane;
      int m = c >> 2, kk = (c & 3) << 3;
      const ushort* ga = A + (size_t)(row0 + m) * K + (k0 + kk);
      ushort* la = Als + (size_t)(is * 256 + wu * 64) * 8;
      __builtin_amdgcn_global_load_lds(
          (const __attribute__((address_space(1))) void*)ga,
          (__attribute__((address_space(3))) void*)la, 16, 0, 0);
    }
    {
      int c = wu * 64 + lane;
      int m = c >> 2, kk = (c & 3) << 3;
      const ushort* gb = Bt + (size_t)(col0 + m) * K + (k0 + kk);
      ushort* lb = Bls + (size_t)(wu * 64) * 8;
      __builtin_amdgcn_global_load_lds(
          (const __attribute__((address_space(1))) void*)gb,
          (__attribute__((address_space(3))) void*)lb, 16, 0, 0);
    }
    __syncthreads();

    short8 af[2], bf[4];
#pragma unroll
    for (int mt = 0; mt < 2; mt++)
      af[mt] = *(const short8*)(Als + ((wu * 32 + mt * 16 + l16) * 32 + quad * 8));
#pragma unroll
    for (int nt = 0; nt < 4; nt++)
      bf[nt] = *(const short8*)(Bls + ((nt * 16 + l16) * 32 + quad * 8));
#pragma unroll
    for (int mt = 0; mt < 2; mt++)
#pragma unroll
      for (int nt = 0; nt < 4; nt++)
        acc[mt][nt] = __builtin_amdgcn_mfma_f32_16x16x32_bf16(
            af[mt], bf[nt], acc[mt][nt], 0, 0, 0);
  }

#pragma unroll
  for (int mt = 0; mt < 2; mt++) {
#pragma unroll
    for (int nt = 0; nt < 4; nt++) {
      int colg = col0 + nt * 16 + l16;
      float bv_ = BIAS ? bias[colg] : 0.f;
      int rowg0 = row0 + wu * 32 + mt * 16 + quad * 4;
#pragma unroll
      for (int r = 0; r < 4; r++)
        C[(size_t)(rowg0 + r) * N + colg] = f2b(acc[mt][nt][r] + bv_);
    }
  }
}

// ---------------------------------------------------------------------------
// MFMA flash attention v11 (R5-verified). UNCHANGED.
// ---------------------------------------------------------------------------
__global__ __launch_bounds__(256, 3) void attn_mfma_kernel(
    const ushort* __restrict__ Q, const ushort* __restrict__ K,
    const ushort* __restrict__ Vt, const float* __restrict__ mask,
    ushort* __restrict__ O) {
  // bijective decode: bid = (slot*8 + qt)*8 + xcd ; grp = slot*8 + xcd
  const int bid  = blockIdx.x;          // 768 blocks
  const int xcd  = bid & 7;
  const int rest = bid >> 3;            // 0..95
  const int qt   = rest & 7;
  const int grp  = (rest >> 3) * 8 + xcd;   // 0..95, grp%8 == xcd
  const int h = grp % 12, b = grp / 12;

  const int tid = threadIdx.x;
  const int lane = tid & 63;
  const int quad = lane >> 4, l16 = lane & 15;
  const int wu = __builtin_amdgcn_readfirstlane(tid >> 6);
  const int qrow0 = qt * 128 + wu * 32;

  __shared__ __align__(16) ushort Ks[2][64 * 64];   // [buf][key][dh], swz slots
  __shared__ __align__(16) ushort Vts[2][64 * 64];  // [buf][dh][key], swz slots
  __shared__ __align__(16) float Msk[SEQ];          // whole mask row

  // one-time mask row preload (1024 floats, one float4/thread)
  *(float4*)(Msk + tid * 4) = *(const float4*)(mask + (size_t)b * SEQ + tid * 4);

  short8 qf[2][2];
#pragma unroll
  for (int rt = 0; rt < 2; rt++) {
    const ushort* qp = Q + ((size_t)(b * SEQ + qrow0 + rt * 16 + l16)) * D_MODEL
                     + h * DHEAD + quad * 8;
    qf[rt][0] = *(const short8*)qp;
    qf[rt][1] = *(const short8*)(qp + 32);
  }

  // staging decomposition: 64 rows x 8 slots, 2 rounds of 32 rows
  const int j0 = tid >> 3, ck = tid & 7;
  const ushort* Kg = K + ((size_t)(b * SEQ + j0)) * D_MODEL + h * DHEAD + ck * 8;
  const ushort* Vg = Vt + ((size_t)(h * DHEAD + j0)) * BM + b * SEQ + ck * 8;
  const int kloff = j0 * 64 + ((ck ^ (j0 & 7)) << 3);   // (row&7) const over p

  // prologue: chunk 0 -> regs -> buf0; then issue chunk-1 loads
  short8 kst[2], vst[2];
#pragma unroll
  for (int p = 0; p < 2; p++) {
    kst[p] = *(const short8*)(Kg + (size_t)(p * 32) * D_MODEL);
    vst[p] = *(const short8*)(Vg + (size_t)p * (32 * BM));
  }
#pragma unroll
  for (int p = 0; p < 2; p++) {
    *(short8*)(&Ks[0][0] + kloff + p * (32 * 64)) = kst[p];
    *(short8*)(&Vts[0][0] + kloff + p * (32 * 64)) = vst[p];
  }
#pragma unroll
  for (int p = 0; p < 2; p++) {
    kst[p] = *(const short8*)(Kg + (size_t)(64 + p * 32) * D_MODEL);
    vst[p] = *(const short8*)(Vg + 64 + (size_t)p * (32 * BM));
  }
  asm volatile("s_waitcnt lgkmcnt(0)" ::: "memory");
  __builtin_amdgcn_s_barrier();
  asm volatile("" ::: "memory");

  float lsum[2] = {0.f, 0.f};
  floatx4 o_acc[2][4] = {};

  for (int n0 = 0; n0 < SEQ; n0 += 64) {
    const int cur = (n0 >> 6) & 1;

    // (1) write staged regs (chunk i+1) -> buf[cur^1]
    if (n0 + 64 < SEQ) {
#pragma unroll
      for (int p = 0; p < 2; p++) {
        *(short8*)(&Ks[cur ^ 1][0] + kloff + p * (32 * 64)) = kst[p];
        *(short8*)(&Vts[cur ^ 1][0] + kloff + p * (32 * 64)) = vst[p];
      }
      // (2) issue chunk i+2 global loads (land during compute below)
      if (n0 + 128 < SEQ) {
#pragma unroll
        for (int p = 0; p < 2; p++) {
          kst[p] = *(const short8*)(Kg + (size_t)(n0 + 128 + p * 32) * D_MODEL);
          vst[p] = *(const short8*)(Vg + (n0 + 128) + (size_t)p * (32 * BM));
        }
      }
    }

    // (3) compute chunk i from buf[cur]
    __builtin_amdgcn_s_setprio(1);
    unsigned UA[2][4], UB[2][4];
#pragma unroll
    for (int ct = 0; ct < 4; ct++) {
      int krow = ct * 16 + l16;
      int sa = (quad ^ (l16 & 7)) << 3;                 // swizzled 16B slot
      const ushort* kbp = &Ks[cur][0] + krow * 64;
      short8 ka = *(const short8*)(kbp + sa);           // K[krow][quad*8..]
      short8 kb = *(const short8*)(kbp + (sa ^ 32));    // K[krow][32+quad*8..]
      float4 mk = *(const float4*)(Msk + n0 + ct * 16 + quad * 4);
#pragma unroll
      for (int rt = 0; rt < 2; rt++) {
        floatx4 st = {};
        st = __builtin_amdgcn_mfma_f32_16x16x32_bf16(ka, qf[rt][0], st, 0, 0, 0);
        st = __builtin_amdgcn_mfma_f32_16x16x32_bf16(kb, qf[rt][1], st, 0, 0, 0);
        float e0 = __expf(st[0] + mk.x);     // Q pre-scaled by 1/sqrt(dh)
        float e1 = __expf(st[1] + mk.y);
        float e2 = __expf(st[2] + mk.z);
        float e3 = __expf(st[3] + mk.w);
        lsum[rt] += (e0 + e1) + (e2 + e3);
        UA[rt][ct] = pk2(e0, e1);            // keys quad*4+0,1 (query l16)
        UB[rt][ct] = pk2(e2, e3);            // keys quad*4+2,3
      }
    }

#pragma unroll
    for (int kk = 0; kk < 2; kk++) {
      short8 pa[2];
#pragma unroll
      for (int rt = 0; rt < 2; rt++) {
        // in-register P transpose: dest quad q, dword w <- keys q*8+2w,+2w+1
        unsigned a0 = UA[rt][2 * kk], a2 = UA[rt][2 * kk + 1];
        unsigned b1 = UB[rt][2 * kk], b3 = UB[rt][2 * kk + 1];
        asm("v_permlane32_swap_b32 %0, %1" : "+v"(a0), "+v"(a2));
        asm("v_permlane16_swap_b32 %0, %1" : "+v"(a0), "+v"(a2));
        asm("v_permlane32_swap_b32 %0, %1" : "+v"(b1), "+v"(b3));
        asm("v_permlane16_swap_b32 %0, %1" : "+v"(b1), "+v"(b3));
        int4 t;
        t.x = (int)a0;   // keys q*8+0,1
        t.y = (int)b1;   // keys q*8+2,3
        t.z = (int)a2;   // keys q*8+4,5
        t.w = (int)b3;   // keys q*8+6,7
        pa[rt] = *(short8*)&t;
      }
#pragma unroll
      for (int dt = 0; dt < 4; dt++) {
        int vr = dt * 16 + l16;
        short8 vb = *(const short8*)(&Vts[cur][0] + vr * 64
                                     + (((kk * 4 + quad) ^ (l16 & 7)) << 3));
#pragma unroll
        for (int rt = 0; rt < 2; rt++)
          o_acc[rt][dt] = __builtin_amdgcn_mfma_f32_16x16x32_bf16(
              pa[rt], vb, o_acc[rt][dt], 0, 0, 0);
      }
    }
    __builtin_amdgcn_s_setprio(0);

    // (4) one barrier per chunk (drain own ds_writes first)
    if (n0 + 64 < SEQ) {
      asm volatile("s_waitcnt lgkmcnt(0)" ::: "memory");
      __builtin_amdgcn_s_barrier();
      asm volatile("" ::: "memory");
    }
  }

#pragma unroll
  for (int rt = 0; rt < 2; rt++) {
    float l = lsum[rt];
    l += __shfl_xor(l, 16);
    l += __shfl_xor(l, 32);
    float inv = 1.f / l;
    int lanebase = lane & 48;
#pragma unroll
    for (int rr = 0; rr < 4; rr++) {
      int iv = __builtin_amdgcn_ds_bpermute((lanebase | (quad * 4 + rr)) << 2,
                                            __float_as_int(inv));
      float invr = __int_as_float(iv);
      size_t rowg = (size_t)(b * SEQ + qrow0 + rt * 16 + quad * 4 + rr);
#pragma unroll
      for (int dt = 0; dt < 4; dt++)
        O[rowg * D_MODEL + h * DHEAD + dt * 16 + l16] = f2b(o_acc[rt][dt][rr] * invr);
    }
  }
}

// ---------------------------------------------------------------------------
// out = LayerNorm(Ain + Bin)*g + bt. Bin bf16. Ain fp32 or bf16.
// R11: one WAVE per row (4 rows/block, grid BM/4): values held in registers
// (12/lane), two 6-step __shfl_xor reductions, ZERO barriers / LDS.
// ---------------------------------------------------------------------------
template <int AIN_BF16, int OUT_FP32, int OUT_BF16>
__global__ __launch_bounds__(256) void add_ln_kernel(
    const float* __restrict__ Ainf, const ushort* __restrict__ Ainb,
    const ushort* __restrict__ Binb,
    const float* __restrict__ g, const float* __restrict__ bt,
    float* __restrict__ outf, ushort* __restrict__ outb) {
  const int lane = threadIdx.x & 63;
  const int row  = blockIdx.x * 4 + (threadIdx.x >> 6);
  const size_t base = (size_t)row * 768;
  float v[12];
  float s = 0.f;
#pragma unroll
  for (int u = 0; u < 12; u++) {
    int c = lane + u * 64;
    float a = AIN_BF16 ? b2f(Ainb[base + c]) : Ainf[base + c];
    v[u] = a + b2f(Binb[base + c]);
    s += v[u];
  }
#pragma unroll
  for (int off = 32; off > 0; off >>= 1) s += __shfl_xor(s, off);
  float mu = s * (1.f / 768.f);
  float s2 = 0.f;
#pragma unroll
  for (int u = 0; u < 12; u++) { float d = v[u] - mu; s2 += d * d; }
#pragma unroll
  for (int off = 32; off > 0; off >>= 1) s2 += __shfl_xor(s2, off);
  float inv = rsqrtf(s2 * (1.f / 768.f) + 1e-12f);
#pragma unroll
  for (int u = 0; u < 12; u++) {
    int c = lane + u * 64;
    float r = g[c] * (v[u] - mu) * inv + bt[c];
    if (OUT_FP32) outf[base + c] = r;
    if (OUT_BF16) outb[base + c] = f2b(r);
  }
}

// ---------------------------------------------------------------------------
extern "C" void kernel_launch(void* const* d_in, const int* in_sizes, int n_in,
                              void* d_out, int out_size, void* d_ws, size_t ws_size,
                              hipStream_t stream) {
  const float* x    = (const float*)d_in[0];
  const float* mask = (const float*)d_in[1];
  const float* Pq   = (const float*)d_in[2];
  const float* Vq   = (const float*)d_in[3];
  const float* bq   = (const float*)d_in[4];
  const float* Pk   = (const float*)d_in[5];
  const float* Vk   = (const float*)d_in[6];
  const float* bk   = (const float*)d_in[7];
  const float* Pv   = (const float*)d_in[8];
  const float* Vv   = (const float*)d_in[9];
  const float* bv   = (const float*)d_in[10];
  const float* Uo   = (const float*)d_in[11];
  const float* Vo   = (const float*)d_in[12];
  const float* bo   = (const float*)d_in[13];
  const float* U1   = (const float*)d_in[14];
  const float* V1   = (const float*)d_in[15];
  const float* b1   = (const float*)d_in[16];
  const float* U2   = (const float*)d_in[17];
  const float* V2   = (const float*)d_in[18];
  const float* b2   = (const float*)d_in[19];
  const float* g1   = (const float*)d_in[20];
  const float* be1  = (const float*)d_in[21];
  const float* g2   = (const float*)d_in[22];
  const float* be2  = (const float*)d_in[23];

  // --- workspace carve (bytes, 256-aligned) ---
  char* w = (char*)d_ws;
  auto alloc = [&](size_t bytes) -> char* {
    char* p = w; w += (bytes + 255) & ~(size_t)255; return p;
  };
  ushort* xb     = (ushort*)alloc((size_t)BM * 768 * 2);
  ushort* Wqkvt  = (ushort*)alloc((size_t)2304 * 768 * 2);
  float*  ball   = (float*)alloc(2304 * 4);
  ushort* VoT    = (ushort*)alloc(768 * 384 * 2);   // Vo^T bf16 (A operand)
  ushort* Uob    = (ushort*)alloc(768 * 384 * 2);   // Uo bf16 (Bt operand)
  ushort* Wot    = (ushort*)alloc(768 * 768 * 2);   // Vo^T @ Uo^T = Wo^T
  ushort* U1t    = (ushort*)alloc(384 * 768 * 2);
  ushort* V1t    = (ushort*)alloc((size_t)3072 * 384 * 2);
  ushort* U2t    = (ushort*)alloc((size_t)384 * 3072 * 2);
  ushort* V2t    = (ushort*)alloc(768 * 384 * 2);
  ushort* Qb     = (ushort*)alloc((size_t)BM * 768 * 2);
  ushort* Kb     = (ushort*)alloc((size_t)BM * 768 * 2);
  ushort* Vtb    = (ushort*)alloc((size_t)768 * BM * 2);
  ushort* attnb  = (ushort*)alloc((size_t)BM * 768 * 2);
  ushort* mtb    = (ushort*)alloc((size_t)BM * 384 * 2);   // mid / t2
  ushort* y1b    = (ushort*)alloc((size_t)BM * 768 * 2);
  ushort* x1b    = (ushort*)alloc((size_t)BM * 768 * 2);
  float*  part   = (float*)alloc((size_t)4 * BM * 384 * 4);
  // aliases (dead-buffer reuse)
  ushort* hiddenb = Qb;             // Qb..attnb (50.3 MB) dead after y1 GEMM
  ushort* y2b     = y1b;            // y1b dead after LN1
  float*  outp    = (float*)d_out;

  // 1) conversions / weight prep
  f2b_kernel<<<(BM * 768) / 1024, 256, 0, stream>>>(x, xb, BM * 768);
  combine_qkv_kernel<<<dim3(2304, 3), 256, 0, stream>>>(Pq, Vq, Pk, Vk, Pv, Vv, Wqkvt);
  concat_bias_kernel<<<9, 256, 0, stream>>>(bq, bk, bv, ball);
  prep_weights_kernel<<<3456, 256, 0, stream>>>(U1, V1, U2, V2, Vo, Uo,
                                                U1t, V1t, U2t, V2t, VoT, Uob);
  // Wot[n][d] = sum_r Vo^T[n][r] * Uo[d][r]  (= Wo[d][n], the Bt operand for y1)
  gemm_n64_kernel<0><<<dim3(6, 12), 256, 0, stream>>>(VoT, Uob, nullptr, Wot, 768, 768, 384);

  // 2) fused QKV = x @ [Wq|Wk|Wv] + bias  (bf16 A staging -- R7-verified)
  gemm_mfma_kernel<3, 1, 0><<<dim3(64, 18), 256, 0, stream>>>(
      xb, Wqkvt, ball, Qb, Kb, Vtb, BM, 2304, 768);

  // 3) MFMA flash attention (dbuf 1-barrier pipeline) -> bf16 (B*M, 768)
  attn_mfma_kernel<<<dim3(768), 256, 0, stream>>>(Qb, Kb, Vtb, mask, attnb);

  // 4) attn out-projection: y1 = attn @ Wo + bo  (piped n64: 768 blocks, 3/CU)
  gemm_piped_n64_kernel<1, 0><<<dim3(64, 12), 256, 0, stream>>>(
      attnb, Wot, bo, y1b, BM, 768, 768);
  add_ln_kernel<0, 0, 1><<<BM / 4, 256, 0, stream>>>(x, nullptr, y1b, g1, be1, nullptr, x1b);

  // 5) FFN (low rank) with fast GELU
  gemm_piped_n64_kernel<0, 0><<<dim3(64, 6), 256, 0, stream>>>(
      x1b, U1t, nullptr, mtb, BM, 384, 768);
  gemm_mfma_kernel<1, 1, 1><<<dim3(64, 24), 256, 0, stream>>>(
      mtb, V1t, b1, hiddenb, nullptr, nullptr, BM, 3072, 384);
  //    t2 = hidden @ U2 (K=3072): piped splitk S=2
  gemm_piped_splitk_kernel<<<dim3(64, 3, 2), 256, 0, stream>>>(
      hiddenb, U2t, part, BM, 384, 3072, 1536);
  reduce_splitk_kernel<<<(BM * 384) / 1024, 256, 0, stream>>>(part, mtb, BM * 384, 2);
  gemm_piped_n64_kernel<1, 0><<<dim3(64, 12), 256, 0, stream>>>(
      mtb, V2t, b2, y2b, BM, 768, 384);

  // 6) residual + LN2 -> output (fp32)
  add_ln_kernel<1, 1, 0><<<BM / 4, 256, 0, stream>>>(nullptr, x1b, y2b, g2, be2, outp, nullptr);
}